// Round 3
// baseline (519.132 us; speedup 1.0000x reference)
//
#include <hip/hip_runtime.h>

typedef __bf16 v8bf __attribute__((ext_vector_type(8)));
typedef float  v4f  __attribute__((ext_vector_type(4)));
typedef unsigned short u16;

__device__ __forceinline__ u16 f2bf(float f){
  union { float f; unsigned int i; } v; v.f = f;
  return (u16)((v.i + 0x7fffu + ((v.i >> 16) & 1u)) >> 16);
}
__device__ __forceinline__ v4f v4zero(){ v4f z; z[0]=0.f; z[1]=0.f; z[2]=0.f; z[3]=0.f; return z; }

#define MFMA16(a,b,c) __builtin_amdgcn_mfma_f32_16x16x32_bf16((a),(b),(c),0,0,0)

// async global->LDS, 16B per lane; LDS dest = wave-uniform base + lane*16
__device__ __forceinline__ void gl_lds16(const u16* g, u16* l){
  __builtin_amdgcn_global_load_lds((const __attribute__((address_space(1))) void*)g,
                                   (__attribute__((address_space(3))) void*)l, 16, 0, 0);
}

// ============ f32 -> bf16 bulk convert ============
__global__ __launch_bounds__(256) void cvt_kernel(const float* __restrict__ src, u16* __restrict__ dst, int n){
  int i = (blockIdx.x*256 + threadIdx.x)*4;
  if (i < n){
    float4 v = *(const float4*)(src + i);
    ushort4 o;
    o.x = f2bf(v.x); o.y = f2bf(v.y); o.z = f2bf(v.z); o.w = f2bf(v.w);
    *(ushort4*)(dst + i) = o;
  }
}

// ============ GroupNorm stats: one block per (b,g) ============
__global__ __launch_bounds__(256) void gn_stats_kernel(const float* __restrict__ x, float* __restrict__ stats){
  const float* base = x + (size_t)blockIdx.x * 16384;
  float s = 0.f, ss = 0.f;
  #pragma unroll
  for (int it = 0; it < 16; ++it){
    float4 v = *(const float4*)(base + it*1024 + threadIdx.x*4);
    s  += v.x + v.y + v.z + v.w;
    ss += v.x*v.x + v.y*v.y + v.z*v.z + v.w*v.w;
  }
  #pragma unroll
  for (int off = 32; off > 0; off >>= 1){ s += __shfl_down(s, off); ss += __shfl_down(ss, off); }
  __shared__ float red[8];
  int w = threadIdx.x >> 6;
  if ((threadIdx.x & 63) == 0){ red[w] = s; red[4+w] = ss; }
  __syncthreads();
  if (threadIdx.x == 0){
    float S  = red[0]+red[1]+red[2]+red[3];
    float SS = red[4]+red[5]+red[6]+red[7];
    float mean = S * (1.f/16384.f);
    float var  = SS * (1.f/16384.f) - mean*mean;
    stats[blockIdx.x*2]   = mean;
    stats[blockIdx.x*2+1] = rsqrtf(var + 1e-5f);
  }
}

// ============ GroupNorm apply + transpose: f32 x -> bf16 h_t[b][n][c] ============
__global__ __launch_bounds__(256) void gn_apply_kernel(const float* __restrict__ x, const float* __restrict__ nw,
                                                       const float* __restrict__ nb, const float* __restrict__ stats,
                                                       u16* __restrict__ h_t){
  __shared__ u16 tile[32*520];   // [n_local 32][c 512 + pad 8]
  int b = blockIdx.y, n0 = blockIdx.x*32, tid = threadIdx.x;
  int cr = tid >> 2, nn = (tid & 3)*8;
  #pragma unroll
  for (int p = 0; p < 8; ++p){
    int c = p*64 + cr;
    const float* px = x + (size_t)(b*512 + c)*1024 + n0 + nn;
    float4 u0 = *(const float4*)(px);
    float4 u1 = *(const float4*)(px + 4);
    int g = c >> 4;
    float mean = stats[(b*32+g)*2], rstd = stats[(b*32+g)*2+1];
    float wv = nw[c], bv = nb[c];
    float vals[8] = {u0.x,u0.y,u0.z,u0.w,u1.x,u1.y,u1.z,u1.w};
    #pragma unroll
    for (int e = 0; e < 8; ++e)
      tile[(nn+e)*520 + c] = f2bf((vals[e] - mean)*rstd*wv + bv);
  }
  __syncthreads();
  #pragma unroll
  for (int p = 0; p < 8; ++p){
    int n  = p*4 + (tid >> 6);
    int c0 = (tid & 63)*8;
    *(int4*)(h_t + ((size_t)b*1024 + n0 + n)*512 + c0) = *(int4*)(tile + n*520 + c0);
  }
}

// ============ Generic bf16 GEMM: C[M][N] = A[M][K]*B[N][K]^T, global_load_lds staging ============
// grid (N/128, M/128, batch), 256 threads (4 waves, each 64x64)
__global__ __launch_bounds__(256,2) void gemm_bt_kernel(
    const u16* __restrict__ A, long long sA,
    const u16* __restrict__ B, long long sB,
    u16* __restrict__ Cbf, float* __restrict__ Cf, long long sC,
    const float* __restrict__ bias_row,
    const float* __restrict__ bias_col,
    const float* __restrict__ residf, long long sR,
    int M, int N, int K)
{
  __shared__ u16 smem[18432];   // 36864 B: staging As[128][32]+Bs[128][32]=16KB; epilogue 4x[64][72]
  u16* As = smem;               // [128][32] row-major, unpadded (global_load_lds lane-linear)
  u16* Bs = smem + 128*32;
  const int tid = threadIdx.x, w = tid>>6, lane = tid&63, col = lane&15, quad = lane>>4;
  const int m0 = blockIdx.y*128, n0 = blockIdx.x*128;
  const int lr = lane>>2, lc8 = (lane&3)*8;    // lane -> (row in 16-chunk, k-granule)
  const u16* Ag = A + (size_t)blockIdx.z*sA + (size_t)(m0 + w*32 + lr)*K + lc8;
  const u16* Bg = B + (size_t)blockIdx.z*sB + (size_t)(n0 + w*32 + lr)*K + lc8;
  u16* ldsA = As + (w*32)*32;   // wave-uniform base
  u16* ldsB = Bs + (w*32)*32;
  const int mw = (w&1)*64, nw = (w>>1)*64;

  v4f acc[4][4];
  #pragma unroll
  for (int i=0;i<4;++i)
    #pragma unroll
    for (int j=0;j<4;++j) acc[i][j] = v4zero();

  for (int kt = 0; kt < K; kt += 32){
    gl_lds16(Ag + kt,          ldsA);
    gl_lds16(Ag + 16*K + kt,   ldsA + 16*32);
    gl_lds16(Bg + kt,          ldsB);
    gl_lds16(Bg + 16*K + kt,   ldsB + 16*32);
    __syncthreads();
    v8bf a[4], bb[4];
    #pragma unroll
    for (int i = 0; i < 4; ++i) a[i]  = *(const v8bf*)(As + (mw+i*16+col)*32 + quad*8);
    #pragma unroll
    for (int j = 0; j < 4; ++j) bb[j] = *(const v8bf*)(Bs + (nw+j*16+col)*32 + quad*8);
    #pragma unroll
    for (int i = 0; i < 4; ++i)
      #pragma unroll
      for (int j = 0; j < 4; ++j)
        acc[i][j] = MFMA16(a[i], bb[j], acc[i][j]);
    __syncthreads();
  }

  float br[4][4], bc[4];
  #pragma unroll
  for (int i = 0; i < 4; ++i)
    #pragma unroll
    for (int r = 0; r < 4; ++r)
      br[i][r] = bias_row ? bias_row[m0+mw+i*16+quad*4+r] : 0.f;
  #pragma unroll
  for (int j = 0; j < 4; ++j)
    bc[j] = bias_col ? bias_col[n0+nw+j*16+col] : 0.f;

  if (Cf){
    float* Cb = Cf + (size_t)blockIdx.z*sC;
    const float* Rb = residf ? residf + (size_t)blockIdx.z*sR : nullptr;
    #pragma unroll
    for (int i = 0; i < 4; ++i)
      #pragma unroll
      for (int r = 0; r < 4; ++r){
        int row = m0+mw+i*16+quad*4+r;
        #pragma unroll
        for (int j = 0; j < 4; ++j){
          size_t goff = (size_t)row*N + n0+nw+j*16+col;
          float val = acc[i][j][r] + br[i][r] + bc[j];
          if (Rb) val += Rb[goff];
          Cb[goff] = val;
        }
      }
  } else {
    u16* Cs = smem + w*(64*72);
    #pragma unroll
    for (int i = 0; i < 4; ++i)
      #pragma unroll
      for (int j = 0; j < 4; ++j)
        #pragma unroll
        for (int r = 0; r < 4; ++r)
          Cs[(i*16+quad*4+r)*72 + j*16+col] = f2bf(acc[i][j][r] + br[i][r] + bc[j]);
    __syncthreads();
    u16* Cb = Cbf + (size_t)blockIdx.z*sC;
    #pragma unroll
    for (int p = 0; p < 8; ++p){
      int rl = p*8 + (lane>>3), cl = (lane&7)*8;
      size_t goff = (size_t)(m0+mw+rl)*N + n0+nw+cl;
      *(int4*)(Cb + goff) = *(int4*)(Cs + rl*72 + cl);
    }
  }
}

// ============ Fused flash attention ============
// qk[b][n][0..511]=q, [512..1023]=k; vv[b][c_all][m]; out[b][n][c_all]
// flat grid 512: qt = id>>6 (q-tile), bh = id&63 -> same-(b,h) blocks land on same XCD.
// LDS (34,816 B): Ks[64][128] aliased with Ps[128][64]; Vs[144][64] (row 128 = ones column -> l via MFMA).
// All buffers XOR-swizzled on 8-u16 granules: addr = r*W + ((g ^ (r&7))<<3) + (c&7).
__global__ __launch_bounds__(256,4) void attn_kernel(const u16* __restrict__ qk, const u16* __restrict__ vv,
                                                     u16* __restrict__ outp){
  __shared__ u16 smem[17408];
  u16* KP = smem;               // Ks [64][128] / Ps [128][64] (aliased)
  u16* Vs = smem + 8192;        // [144][64]
  const int id = blockIdx.x;
  const int qt = id >> 6, bh = id & 63, b = bh >> 2, h = bh & 3;
  const int n0 = qt*128;
  const int tid = threadIdx.x, w = tid>>6, lane = tid&63, col = lane&15, quad = lane>>4;
  const size_t bq = (size_t)b*1024*1024;
  const float scale2 = 0.12751742f;  // (1/sqrt(128)) * log2(e)

  // ones column: Vs rows 128..143 (row 128 = 1.0, rest 0)
  if (tid < 128){
    int r = 128 + (tid>>3);
    int gm = (tid&7) ^ (r&7);
    int pat = (r == 128) ? (int)0x3F803F80u : 0;
    int4 v; v.x = pat; v.y = pat; v.z = pat; v.w = pat;
    *(int4*)(Vs + (r<<6) + (gm<<3)) = v;
  }

  // Q fragments in registers for the whole kernel (A-operand layout)
  v8bf aq[2][4];
  #pragma unroll
  for (int i = 0; i < 2; ++i)
    #pragma unroll
    for (int kk = 0; kk < 4; ++kk)
      aq[i][kk] = *(const v8bf*)(qk + bq + (size_t)(n0 + w*32 + i*16 + col)*1024 + h*128 + kk*32 + quad*8);

  v4f o[2][9];
  #pragma unroll
  for (int i=0;i<2;++i)
    #pragma unroll
    for (int j=0;j<9;++j) o[i][j] = v4zero();
  float mi[8];
  #pragma unroll
  for (int r=0;r<8;++r) mi[r] = -1e30f;

  for (int mt = 0; mt < 1024; mt += 64){
    #pragma unroll
    for (int p = 0; p < 4; ++p){
      int r = p*16 + (tid>>4);
      int gc = (tid&15) ^ (r&7);
      *(int4*)(KP + (r<<7) + (gc<<3)) =
        *(const int4*)(qk + bq + (size_t)(mt + r)*1024 + 512 + h*128 + ((tid&15)<<3));
    }
    #pragma unroll
    for (int p = 0; p < 4; ++p){
      int r = p*32 + (tid>>3);
      int gm = (tid&7) ^ (r&7);
      *(int4*)(Vs + (r<<6) + (gm<<3)) =
        *(const int4*)(vv + ((size_t)b*512 + h*128 + r)*1024 + mt + ((tid&7)<<3));
    }
    __syncthreads();                               // (A) staging visible

    // S = Q K^T (raw, unscaled)
    v4f s[2][4];
    #pragma unroll
    for (int i=0;i<2;++i)
      #pragma unroll
      for (int j=0;j<4;++j) s[i][j] = v4zero();
    #pragma unroll
    for (int kk = 0; kk < 4; ++kk){
      v8bf bk[4];
      #pragma unroll
      for (int j = 0; j < 4; ++j){
        int r = j*16 + col;
        int g = (kk*4 + quad) ^ (r&7);
        bk[j] = *(const v8bf*)(KP + (r<<7) + (g<<3));
      }
      #pragma unroll
      for (int i = 0; i < 2; ++i)
        #pragma unroll
        for (int j = 0; j < 4; ++j)
          s[i][j] = MFMA16(aq[i][kk], bk[j], s[i][j]);
    }
    __syncthreads();                               // (B) all Ks reads done (KP becomes Ps)

    // online softmax (base-2 domain); row-sum comes free via ones column
    #pragma unroll
    for (int i = 0; i < 2; ++i)
      #pragma unroll
      for (int r = 0; r < 4; ++r){
        float mx = fmaxf(fmaxf(s[i][0][r], s[i][1][r]), fmaxf(s[i][2][r], s[i][3][r]));
        mx = fmaxf(mx, __shfl_xor(mx, 1));
        mx = fmaxf(mx, __shfl_xor(mx, 2));
        mx = fmaxf(mx, __shfl_xor(mx, 4));
        mx = fmaxf(mx, __shfl_xor(mx, 8));
        int ir = i*4 + r;
        float mnew  = fmaxf(mi[ir], mx*scale2);
        float alpha = exp2f(mi[ir] - mnew);
        mi[ir] = mnew;
        #pragma unroll
        for (int j = 0; j < 4; ++j)
          s[i][j][r] = exp2f(fmaf(s[i][j][r], scale2, -mnew));
        #pragma unroll
        for (int j = 0; j < 9; ++j) o[i][j][r] *= alpha;
      }

    // P -> Ps (A-operand layout via LDS)
    #pragma unroll
    for (int i = 0; i < 2; ++i)
      #pragma unroll
      for (int j = 0; j < 4; ++j)
        #pragma unroll
        for (int r = 0; r < 4; ++r){
          int rr = w*32 + i*16 + quad*4 + r;
          int m  = j*16 + col;
          KP[(rr<<6) + ((((m>>3) ^ (rr&7))<<3)) + (m&7)] = f2bf(s[i][j][r]);
        }
    __syncthreads();                               // (C) Ps visible

    // O += P [V; ones]^T
    #pragma unroll
    for (int kk = 0; kk < 2; ++kk){
      v8bf ap[2];
      #pragma unroll
      for (int i = 0; i < 2; ++i){
        int rr = w*32 + i*16 + col;
        int g = (kk*4 + quad) ^ (rr&7);
        ap[i] = *(const v8bf*)(KP + (rr<<6) + (g<<3));
      }
      #pragma unroll
      for (int j = 0; j < 9; ++j){
        int vr = j*16 + col;
        int g = (kk*4 + quad) ^ (vr&7);
        v8bf bv = *(const v8bf*)(Vs + (vr<<6) + (g<<3));
        #pragma unroll
        for (int i = 0; i < 2; ++i) o[i][j] = MFMA16(ap[i], bv, o[i][j]);
      }
    }
    __syncthreads();                               // (D) PV done; safe to restage
  }

  // normalize: l lives in ones-column (col 0 of j=8 tile), broadcast within quad
  #pragma unroll
  for (int i = 0; i < 2; ++i)
    #pragma unroll
    for (int r = 0; r < 4; ++r){
      float l = __shfl(o[i][8][r], quad<<4);
      float inv = 1.f / l;
      #pragma unroll
      for (int j = 0; j < 8; ++j) o[i][j][r] *= inv;
    }

  // bounce O through LDS (swizzled [128][128]) for coalesced 16B stores
  #pragma unroll
  for (int i = 0; i < 2; ++i)
    #pragma unroll
    for (int j = 0; j < 8; ++j)
      #pragma unroll
      for (int r = 0; r < 4; ++r){
        int rr = w*32 + i*16 + quad*4 + r;
        int c  = j*16 + col;
        smem[(rr<<7) + ((((c>>3) ^ (rr&7))<<3)) + (c&7)] = f2bf(o[i][j][r]);
      }
  __syncthreads();
  #pragma unroll
  for (int p = 0; p < 8; ++p){
    int nr = p*16 + (tid>>4);
    int gc = (tid&15) ^ (nr&7);
    *(int4*)(outp + ((size_t)b*1024 + n0 + nr)*512 + h*128 + ((tid&15)<<3)) =
      *(int4*)(smem + (nr<<7) + (gc<<3));
  }
}

extern "C" void kernel_launch(void* const* d_in, const int* in_sizes, int n_in,
                              void* d_out, int out_size, void* d_ws, size_t ws_size,
                              hipStream_t stream){
  const float* x      = (const float*)d_in[0];
  const float* norm_w = (const float*)d_in[1];
  const float* norm_b = (const float*)d_in[2];
  const float* qkv_w  = (const float*)d_in[3];
  const float* qkv_b  = (const float*)d_in[4];
  const float* proj_w = (const float*)d_in[5];
  const float* proj_b = (const float*)d_in[6];
  float* out = (float*)d_out;

  u16* h_t   = (u16*)d_ws;                                  // [16][1024][512]
  u16* qk_t  = h_t  + (size_t)16*1024*512;                  // [16][1024][1024]
  u16* v_ws  = qk_t + (size_t)16*1024*1024;                 // [16][512][1024]
  u16* wq_bf = v_ws + (size_t)16*512*1024;                  // [1536][512]
  u16* wp_bf = wq_bf + (size_t)1536*512;                    // [512][512]
  float* stats = (float*)(wp_bf + (size_t)512*512);         // [512][2]
  u16* attnout = h_t;                                       // reuse

  cvt_kernel<<<768, 256, 0, stream>>>(qkv_w, wq_bf, 1536*512);
  cvt_kernel<<<256, 256, 0, stream>>>(proj_w, wp_bf, 512*512);
  gn_stats_kernel<<<512, 256, 0, stream>>>(x, stats);
  gn_apply_kernel<<<dim3(32,16), 256, 0, stream>>>(x, norm_w, norm_b, stats, h_t);

  gemm_bt_kernel<<<dim3(8,8,16), 256, 0, stream>>>(
      h_t, (long long)1024*512, wq_bf, 0,
      qk_t, nullptr, (long long)1024*1024, nullptr, qkv_b, nullptr, 0, 1024, 1024, 512);

  gemm_bt_kernel<<<dim3(8,4,16), 256, 0, stream>>>(
      wq_bf + (size_t)1024*512, 0, h_t, (long long)1024*512,
      v_ws, nullptr, (long long)512*1024, qkv_b + 1024, nullptr, nullptr, 0, 512, 1024, 512);

  attn_kernel<<<512, 256, 0, stream>>>(qk_t, v_ws, attnout);

  gemm_bt_kernel<<<dim3(8,4,16), 256, 0, stream>>>(
      wp_bf, 0, attnout, (long long)1024*512,
      nullptr, out, (long long)512*1024, proj_b, nullptr, x, (long long)512*1024, 512, 1024, 512);
}

// Round 4
// 410.972 us; speedup vs baseline: 1.2632x; 1.2632x over previous
//
#include <hip/hip_runtime.h>

typedef __bf16 v8bf __attribute__((ext_vector_type(8)));
typedef float  v4f  __attribute__((ext_vector_type(4)));
typedef unsigned short u16;

__device__ __forceinline__ u16 f2bf(float f){
  union { float f; unsigned int i; } v; v.f = f;
  return (u16)((v.i + 0x7fffu + ((v.i >> 16) & 1u)) >> 16);
}
__device__ __forceinline__ v4f v4zero(){ v4f z; z[0]=0.f; z[1]=0.f; z[2]=0.f; z[3]=0.f; return z; }

#define MFMA16(a,b,c) __builtin_amdgcn_mfma_f32_16x16x32_bf16((a),(b),(c),0,0,0)

// async global->LDS, 16B per lane; LDS dest = wave-uniform base + lane*16
__device__ __forceinline__ void gl_lds16(const u16* g, u16* l){
  __builtin_amdgcn_global_load_lds((const __attribute__((address_space(1))) void*)g,
                                   (__attribute__((address_space(3))) void*)l, 16, 0, 0);
}

// ============ f32 -> bf16 bulk convert ============
__global__ __launch_bounds__(256) void cvt_kernel(const float* __restrict__ src, u16* __restrict__ dst, int n){
  int i = (blockIdx.x*256 + threadIdx.x)*4;
  if (i < n){
    float4 v = *(const float4*)(src + i);
    ushort4 o;
    o.x = f2bf(v.x); o.y = f2bf(v.y); o.z = f2bf(v.z); o.w = f2bf(v.w);
    *(ushort4*)(dst + i) = o;
  }
}

// ============ GroupNorm stats: one block per (b,g) ============
__global__ __launch_bounds__(256) void gn_stats_kernel(const float* __restrict__ x, float* __restrict__ stats){
  const float* base = x + (size_t)blockIdx.x * 16384;
  float s = 0.f, ss = 0.f;
  #pragma unroll
  for (int it = 0; it < 16; ++it){
    float4 v = *(const float4*)(base + it*1024 + threadIdx.x*4);
    s  += v.x + v.y + v.z + v.w;
    ss += v.x*v.x + v.y*v.y + v.z*v.z + v.w*v.w;
  }
  #pragma unroll
  for (int off = 32; off > 0; off >>= 1){ s += __shfl_down(s, off); ss += __shfl_down(ss, off); }
  __shared__ float red[8];
  int w = threadIdx.x >> 6;
  if ((threadIdx.x & 63) == 0){ red[w] = s; red[4+w] = ss; }
  __syncthreads();
  if (threadIdx.x == 0){
    float S  = red[0]+red[1]+red[2]+red[3];
    float SS = red[4]+red[5]+red[6]+red[7];
    float mean = S * (1.f/16384.f);
    float var  = SS * (1.f/16384.f) - mean*mean;
    stats[blockIdx.x*2]   = mean;
    stats[blockIdx.x*2+1] = rsqrtf(var + 1e-5f);
  }
}

// ============ GroupNorm apply + transpose: f32 x -> bf16 h_t[b][n][c] ============
__global__ __launch_bounds__(256) void gn_apply_kernel(const float* __restrict__ x, const float* __restrict__ nw,
                                                       const float* __restrict__ nb, const float* __restrict__ stats,
                                                       u16* __restrict__ h_t){
  __shared__ u16 tile[32*520];   // [n_local 32][c 512 + pad 8]
  int b = blockIdx.y, n0 = blockIdx.x*32, tid = threadIdx.x;
  int cr = tid >> 2, nn = (tid & 3)*8;
  #pragma unroll
  for (int p = 0; p < 8; ++p){
    int c = p*64 + cr;
    const float* px = x + (size_t)(b*512 + c)*1024 + n0 + nn;
    float4 u0 = *(const float4*)(px);
    float4 u1 = *(const float4*)(px + 4);
    int g = c >> 4;
    float mean = stats[(b*32+g)*2], rstd = stats[(b*32+g)*2+1];
    float wv = nw[c], bv = nb[c];
    float vals[8] = {u0.x,u0.y,u0.z,u0.w,u1.x,u1.y,u1.z,u1.w};
    #pragma unroll
    for (int e = 0; e < 8; ++e)
      tile[(nn+e)*520 + c] = f2bf((vals[e] - mean)*rstd*wv + bv);
  }
  __syncthreads();
  #pragma unroll
  for (int p = 0; p < 8; ++p){
    int n  = p*4 + (tid >> 6);
    int c0 = (tid & 63)*8;
    *(int4*)(h_t + ((size_t)b*1024 + n0 + n)*512 + c0) = *(int4*)(tile + n*520 + c0);
  }
}

// ============ Generic bf16 GEMM: C[M][N] = A[M][K]*B[N][K]^T ============
// global_load_lds staging with XOR-granule swizzle applied at the SOURCE address
// (lane fetches granule (lane&3)^(row&3)), so fragment ds_read_b128s at granule
// quad^(col&3) hit all 32 banks (2-way = free).
// grid (N/128, M/128, batch), 256 threads (4 waves, each 64x64)
__global__ __launch_bounds__(256,2) void gemm_bt_kernel(
    const u16* __restrict__ A, long long sA,
    const u16* __restrict__ B, long long sB,
    u16* __restrict__ Cbf, float* __restrict__ Cf, long long sC,
    const float* __restrict__ bias_row,
    const float* __restrict__ bias_col,
    const float* __restrict__ residf, long long sR,
    int M, int N, int K)
{
  __shared__ u16 smem[18432];   // staging As[128][32]+Bs[128][32]=16KB; epilogue 4x[64][72]=36KB
  u16* As = smem;               // [128 rows][4 granules of 8], granule swizzled by row&3
  u16* Bs = smem + 128*32;
  const int tid = threadIdx.x, w = tid>>6, lane = tid&63, col = lane&15, quad = lane>>4;
  const int m0 = blockIdx.y*128, n0 = blockIdx.x*128;
  const int lr = lane>>2;
  const int gsw8 = ((lane&3) ^ (lr&3))*8;      // swizzled source granule for this lane
  const u16* Ag = A + (size_t)blockIdx.z*sA + (size_t)(m0 + w*32 + lr)*K + gsw8;
  const u16* Bg = B + (size_t)blockIdx.z*sB + (size_t)(n0 + w*32 + lr)*K + gsw8;
  u16* ldsA = As + (w*32)*32;   // wave-uniform base
  u16* ldsB = Bs + (w*32)*32;
  const int mw = (w&1)*64, nw = (w>>1)*64;
  const int fsw8 = (quad ^ (col&3))*8;         // fragment-read granule

  v4f acc[4][4];
  #pragma unroll
  for (int i=0;i<4;++i)
    #pragma unroll
    for (int j=0;j<4;++j) acc[i][j] = v4zero();

  for (int kt = 0; kt < K; kt += 32){
    gl_lds16(Ag + kt,          ldsA);
    gl_lds16(Ag + 16*K + kt,   ldsA + 16*32);
    gl_lds16(Bg + kt,          ldsB);
    gl_lds16(Bg + 16*K + kt,   ldsB + 16*32);
    __syncthreads();
    v8bf a[4], bb[4];
    #pragma unroll
    for (int i = 0; i < 4; ++i) a[i]  = *(const v8bf*)(As + (mw+i*16+col)*32 + fsw8);
    #pragma unroll
    for (int j = 0; j < 4; ++j) bb[j] = *(const v8bf*)(Bs + (nw+j*16+col)*32 + fsw8);
    #pragma unroll
    for (int i = 0; i < 4; ++i)
      #pragma unroll
      for (int j = 0; j < 4; ++j)
        acc[i][j] = MFMA16(a[i], bb[j], acc[i][j]);
    __syncthreads();
  }

  float br[4][4], bc[4];
  #pragma unroll
  for (int i = 0; i < 4; ++i)
    #pragma unroll
    for (int r = 0; r < 4; ++r)
      br[i][r] = bias_row ? bias_row[m0+mw+i*16+quad*4+r] : 0.f;
  #pragma unroll
  for (int j = 0; j < 4; ++j)
    bc[j] = bias_col ? bias_col[n0+nw+j*16+col] : 0.f;

  if (Cf){
    float* Cb = Cf + (size_t)blockIdx.z*sC;
    const float* Rb = residf ? residf + (size_t)blockIdx.z*sR : nullptr;
    #pragma unroll
    for (int i = 0; i < 4; ++i)
      #pragma unroll
      for (int r = 0; r < 4; ++r){
        int row = m0+mw+i*16+quad*4+r;
        #pragma unroll
        for (int j = 0; j < 4; ++j){
          size_t goff = (size_t)row*N + n0+nw+j*16+col;
          float val = acc[i][j][r] + br[i][r] + bc[j];
          if (Rb) val += Rb[goff];
          Cb[goff] = val;
        }
      }
  } else {
    u16* Cs = smem + w*(64*72);
    #pragma unroll
    for (int i = 0; i < 4; ++i)
      #pragma unroll
      for (int j = 0; j < 4; ++j)
        #pragma unroll
        for (int r = 0; r < 4; ++r)
          Cs[(i*16+quad*4+r)*72 + j*16+col] = f2bf(acc[i][j][r] + br[i][r] + bc[j]);
    __syncthreads();
    u16* Cb = Cbf + (size_t)blockIdx.z*sC;
    #pragma unroll
    for (int p = 0; p < 8; ++p){
      int rl = p*8 + (lane>>3), cl = (lane&7)*8;
      size_t goff = (size_t)(m0+mw+rl)*N + n0+nw+cl;
      *(int4*)(Cb + goff) = *(int4*)(Cs + rl*72 + cl);
    }
  }
}

// ============ Fused flash attention ============
// qk[b][n][0..511]=q, [512..1023]=k; vv[b][c_all][m]; out[b][n][c_all]
// flat grid 512: qt = id>>6, bh = id&63 -> same-(b,h) blocks land on same XCD.
// LDS (34,816 B): Ks[64][128] aliased with Ps[128][64]; Vs[144][64] (row 128 = ones col -> l via MFMA).
// XOR-swizzled on 8-u16 granules: addr = r*W + ((g ^ (r&7))<<3) + (c&7).
__global__ __launch_bounds__(256,3) void attn_kernel(const u16* __restrict__ qk, const u16* __restrict__ vv,
                                                     u16* __restrict__ outp){
  __shared__ u16 smem[17408];
  u16* KP = smem;               // Ks [64][128] / Ps [128][64] (aliased)
  u16* Vs = smem + 8192;        // [144][64]
  const int id = blockIdx.x;
  const int qt = id >> 6, bh = id & 63, b = bh >> 2, h = bh & 3;
  const int n0 = qt*128;
  const int tid = threadIdx.x, w = tid>>6, lane = tid&63, col = lane&15, quad = lane>>4;
  const size_t bq = (size_t)b*1024*1024;
  const float scale2 = 0.12751742f;  // (1/sqrt(128)) * log2(e)

  // ones column: Vs rows 128..143 (row 128 = 1.0, rest 0)
  if (tid < 128){
    int r = 128 + (tid>>3);
    int gm = (tid&7) ^ (r&7);
    int pat = (r == 128) ? (int)0x3F803F80u : 0;
    int4 v; v.x = pat; v.y = pat; v.z = pat; v.w = pat;
    *(int4*)(Vs + (r<<6) + (gm<<3)) = v;
  }

  // Q fragments in registers for the whole kernel (A-operand layout)
  v8bf aq[2][4];
  #pragma unroll
  for (int i = 0; i < 2; ++i)
    #pragma unroll
    for (int kk = 0; kk < 4; ++kk)
      aq[i][kk] = *(const v8bf*)(qk + bq + (size_t)(n0 + w*32 + i*16 + col)*1024 + h*128 + kk*32 + quad*8);

  v4f o[2][9];
  #pragma unroll
  for (int i=0;i<2;++i)
    #pragma unroll
    for (int j=0;j<9;++j) o[i][j] = v4zero();
  float mi[8];
  #pragma unroll
  for (int r=0;r<8;++r) mi[r] = -1e30f;

  for (int mt = 0; mt < 1024; mt += 64){
    #pragma unroll
    for (int p = 0; p < 4; ++p){
      int r = p*16 + (tid>>4);
      int gc = (tid&15) ^ (r&7);
      *(int4*)(KP + (r<<7) + (gc<<3)) =
        *(const int4*)(qk + bq + (size_t)(mt + r)*1024 + 512 + h*128 + ((tid&15)<<3));
    }
    #pragma unroll
    for (int p = 0; p < 4; ++p){
      int r = p*32 + (tid>>3);
      int gm = (tid&7) ^ (r&7);
      *(int4*)(Vs + (r<<6) + (gm<<3)) =
        *(const int4*)(vv + ((size_t)b*512 + h*128 + r)*1024 + mt + ((tid&7)<<3));
    }
    __syncthreads();                               // (A) staging visible

    // S = Q K^T (raw, unscaled)
    v4f s[2][4];
    #pragma unroll
    for (int i=0;i<2;++i)
      #pragma unroll
      for (int j=0;j<4;++j) s[i][j] = v4zero();
    #pragma unroll
    for (int kk = 0; kk < 4; ++kk){
      v8bf bk[4];
      #pragma unroll
      for (int j = 0; j < 4; ++j){
        int r = j*16 + col;
        int g = (kk*4 + quad) ^ (r&7);
        bk[j] = *(const v8bf*)(KP + (r<<7) + (g<<3));
      }
      #pragma unroll
      for (int i = 0; i < 2; ++i)
        #pragma unroll
        for (int j = 0; j < 4; ++j)
          s[i][j] = MFMA16(aq[i][kk], bk[j], s[i][j]);
    }
    __syncthreads();                               // (B) all Ks reads done (KP becomes Ps)

    // online softmax (base-2 domain); row-sum comes free via ones column
    #pragma unroll
    for (int i = 0; i < 2; ++i)
      #pragma unroll
      for (int r = 0; r < 4; ++r){
        float mx = fmaxf(fmaxf(s[i][0][r], s[i][1][r]), fmaxf(s[i][2][r], s[i][3][r]));
        mx = fmaxf(mx, __shfl_xor(mx, 1));
        mx = fmaxf(mx, __shfl_xor(mx, 2));
        mx = fmaxf(mx, __shfl_xor(mx, 4));
        mx = fmaxf(mx, __shfl_xor(mx, 8));
        int ir = i*4 + r;
        float mnew  = fmaxf(mi[ir], mx*scale2);
        float alpha = exp2f(mi[ir] - mnew);
        mi[ir] = mnew;
        #pragma unroll
        for (int j = 0; j < 4; ++j)
          s[i][j][r] = exp2f(fmaf(s[i][j][r], scale2, -mnew));
        #pragma unroll
        for (int j = 0; j < 9; ++j) o[i][j][r] *= alpha;
      }

    // P -> Ps (A-operand layout via LDS)
    #pragma unroll
    for (int i = 0; i < 2; ++i)
      #pragma unroll
      for (int j = 0; j < 4; ++j)
        #pragma unroll
        for (int r = 0; r < 4; ++r){
          int rr = w*32 + i*16 + quad*4 + r;
          int m  = j*16 + col;
          KP[(rr<<6) + ((((m>>3) ^ (rr&7))<<3)) + (m&7)] = f2bf(s[i][j][r]);
        }
    __syncthreads();                               // (C) Ps visible

    // O += P [V; ones]^T
    #pragma unroll
    for (int kk = 0; kk < 2; ++kk){
      v8bf ap[2];
      #pragma unroll
      for (int i = 0; i < 2; ++i){
        int rr = w*32 + i*16 + col;
        int g = (kk*4 + quad) ^ (rr&7);
        ap[i] = *(const v8bf*)(KP + (rr<<6) + (g<<3));
      }
      #pragma unroll
      for (int j = 0; j < 9; ++j){
        int vr = j*16 + col;
        int g = (kk*4 + quad) ^ (vr&7);
        v8bf bv = *(const v8bf*)(Vs + (vr<<6) + (g<<3));
        #pragma unroll
        for (int i = 0; i < 2; ++i) o[i][j] = MFMA16(ap[i], bv, o[i][j]);
      }
    }
    __syncthreads();                               // (D) PV done; safe to restage
  }

  // normalize: l lives in ones-column (col 0 of j=8 tile), broadcast within quad
  #pragma unroll
  for (int i = 0; i < 2; ++i)
    #pragma unroll
    for (int r = 0; r < 4; ++r){
      float l = __shfl(o[i][8][r], quad<<4);
      float inv = 1.f / l;
      #pragma unroll
      for (int j = 0; j < 8; ++j) o[i][j][r] *= inv;
    }

  // bounce O through LDS (swizzled [128][128]) for coalesced 16B stores
  #pragma unroll
  for (int i = 0; i < 2; ++i)
    #pragma unroll
    for (int j = 0; j < 8; ++j)
      #pragma unroll
      for (int r = 0; r < 4; ++r){
        int rr = w*32 + i*16 + quad*4 + r;
        int c  = j*16 + col;
        smem[(rr<<7) + ((((c>>3) ^ (rr&7))<<3)) + (c&7)] = f2bf(o[i][j][r]);
      }
  __syncthreads();
  #pragma unroll
  for (int p = 0; p < 8; ++p){
    int nr = p*16 + (tid>>4);
    int gc = (tid&15) ^ (nr&7);
    *(int4*)(outp + ((size_t)b*1024 + n0 + nr)*512 + h*128 + ((tid&15)<<3)) =
      *(int4*)(smem + (nr<<7) + (gc<<3));
  }
}

extern "C" void kernel_launch(void* const* d_in, const int* in_sizes, int n_in,
                              void* d_out, int out_size, void* d_ws, size_t ws_size,
                              hipStream_t stream){
  const float* x      = (const float*)d_in[0];
  const float* norm_w = (const float*)d_in[1];
  const float* norm_b = (const float*)d_in[2];
  const float* qkv_w  = (const float*)d_in[3];
  const float* qkv_b  = (const float*)d_in[4];
  const float* proj_w = (const float*)d_in[5];
  const float* proj_b = (const float*)d_in[6];
  float* out = (float*)d_out;

  u16* h_t   = (u16*)d_ws;                                  // [16][1024][512]
  u16* qk_t  = h_t  + (size_t)16*1024*512;                  // [16][1024][1024]
  u16* v_ws  = qk_t + (size_t)16*1024*1024;                 // [16][512][1024]
  u16* wq_bf = v_ws + (size_t)16*512*1024;                  // [1536][512]
  u16* wp_bf = wq_bf + (size_t)1536*512;                    // [512][512]
  float* stats = (float*)(wp_bf + (size_t)512*512);         // [512][2]
  u16* attnout = h_t;                                       // reuse

  cvt_kernel<<<768, 256, 0, stream>>>(qkv_w, wq_bf, 1536*512);
  cvt_kernel<<<256, 256, 0, stream>>>(proj_w, wp_bf, 512*512);
  gn_stats_kernel<<<512, 256, 0, stream>>>(x, stats);
  gn_apply_kernel<<<dim3(32,16), 256, 0, stream>>>(x, norm_w, norm_b, stats, h_t);

  gemm_bt_kernel<<<dim3(8,8,16), 256, 0, stream>>>(
      h_t, (long long)1024*512, wq_bf, 0,
      qk_t, nullptr, (long long)1024*1024, nullptr, qkv_b, nullptr, 0, 1024, 1024, 512);

  gemm_bt_kernel<<<dim3(8,4,16), 256, 0, stream>>>(
      wq_bf + (size_t)1024*512, 0, h_t, (long long)1024*512,
      v_ws, nullptr, (long long)512*1024, qkv_b + 1024, nullptr, nullptr, 0, 512, 1024, 512);

  attn_kernel<<<512, 256, 0, stream>>>(qk_t, v_ws, attnout);

  gemm_bt_kernel<<<dim3(8,4,16), 256, 0, stream>>>(
      wp_bf, 0, attnout, (long long)1024*512,
      nullptr, out, (long long)512*1024, proj_b, nullptr, x, (long long)512*1024, 512, 1024, 512);
}

// Round 5
// 271.550 us; speedup vs baseline: 1.9117x; 1.5134x over previous
//
#include <hip/hip_runtime.h>

typedef __bf16 v8bf __attribute__((ext_vector_type(8)));
typedef float  v4f  __attribute__((ext_vector_type(4)));
typedef unsigned short u16;

__device__ __forceinline__ u16 f2bf(float f){
  union { float f; unsigned int i; } v; v.f = f;
  return (u16)((v.i + 0x7fffu + ((v.i >> 16) & 1u)) >> 16);
}
__device__ __forceinline__ v4f v4zero(){ v4f z; z[0]=0.f; z[1]=0.f; z[2]=0.f; z[3]=0.f; return z; }

#define MFMA16(a,b,c) __builtin_amdgcn_mfma_f32_16x16x32_bf16((a),(b),(c),0,0,0)

// async global->LDS, 16B per lane; LDS dest = wave-uniform base + lane*16
__device__ __forceinline__ void gl_lds16(const u16* g, u16* l){
  __builtin_amdgcn_global_load_lds((const __attribute__((address_space(1))) void*)g,
                                   (__attribute__((address_space(3))) void*)l, 16, 0, 0);
}

// ============ f32 -> bf16 bulk convert ============
__global__ __launch_bounds__(256) void cvt_kernel(const float* __restrict__ src, u16* __restrict__ dst, int n){
  int i = (blockIdx.x*256 + threadIdx.x)*4;
  if (i < n){
    float4 v = *(const float4*)(src + i);
    ushort4 o;
    o.x = f2bf(v.x); o.y = f2bf(v.y); o.z = f2bf(v.z); o.w = f2bf(v.w);
    *(ushort4*)(dst + i) = o;
  }
}

// ============ GroupNorm stats: one block per (b,g) ============
__global__ __launch_bounds__(256) void gn_stats_kernel(const float* __restrict__ x, float* __restrict__ stats){
  const float* base = x + (size_t)blockIdx.x * 16384;
  float s = 0.f, ss = 0.f;
  #pragma unroll
  for (int it = 0; it < 16; ++it){
    float4 v = *(const float4*)(base + it*1024 + threadIdx.x*4);
    s  += v.x + v.y + v.z + v.w;
    ss += v.x*v.x + v.y*v.y + v.z*v.z + v.w*v.w;
  }
  #pragma unroll
  for (int off = 32; off > 0; off >>= 1){ s += __shfl_down(s, off); ss += __shfl_down(ss, off); }
  __shared__ float red[8];
  int w = threadIdx.x >> 6;
  if ((threadIdx.x & 63) == 0){ red[w] = s; red[4+w] = ss; }
  __syncthreads();
  if (threadIdx.x == 0){
    float S  = red[0]+red[1]+red[2]+red[3];
    float SS = red[4]+red[5]+red[6]+red[7];
    float mean = S * (1.f/16384.f);
    float var  = SS * (1.f/16384.f) - mean*mean;
    stats[blockIdx.x*2]   = mean;
    stats[blockIdx.x*2+1] = rsqrtf(var + 1e-5f);
  }
}

// ============ GroupNorm apply + transpose: f32 x -> bf16 h_t[b][n][c] ============
__global__ __launch_bounds__(256) void gn_apply_kernel(const float* __restrict__ x, const float* __restrict__ nw,
                                                       const float* __restrict__ nb, const float* __restrict__ stats,
                                                       u16* __restrict__ h_t){
  __shared__ u16 tile[32*520];   // [n_local 32][c 512 + pad 8]
  int b = blockIdx.y, n0 = blockIdx.x*32, tid = threadIdx.x;
  int cr = tid >> 2, nn = (tid & 3)*8;
  #pragma unroll
  for (int p = 0; p < 8; ++p){
    int c = p*64 + cr;
    const float* px = x + (size_t)(b*512 + c)*1024 + n0 + nn;
    float4 u0 = *(const float4*)(px);
    float4 u1 = *(const float4*)(px + 4);
    int g = c >> 4;
    float mean = stats[(b*32+g)*2], rstd = stats[(b*32+g)*2+1];
    float wv = nw[c], bv = nb[c];
    float vals[8] = {u0.x,u0.y,u0.z,u0.w,u1.x,u1.y,u1.z,u1.w};
    #pragma unroll
    for (int e = 0; e < 8; ++e)
      tile[(nn+e)*520 + c] = f2bf((vals[e] - mean)*rstd*wv + bv);
  }
  __syncthreads();
  #pragma unroll
  for (int p = 0; p < 8; ++p){
    int n  = p*4 + (tid >> 6);
    int c0 = (tid & 63)*8;
    *(int4*)(h_t + ((size_t)b*1024 + n0 + n)*512 + c0) = *(int4*)(tile + n*520 + c0);
  }
}

// ============ Generic bf16 GEMM: C[M][N] = A[M][K]*B[N][K]^T, BK=64 ============
// global_load_lds staging; XOR-granule swizzle folded into SOURCE addresses so
// fragment ds_read_b128s hit all 32 banks (2-way = free). Rows start at bank 0
// (128B row), granule slot s of row r holds global granule s^(r&7).
// grid (N/128, M/128, batch), 256 threads (4 waves, each 64x64)
__global__ __launch_bounds__(256,2) void gemm_bt_kernel(
    const u16* __restrict__ A, long long sA,
    const u16* __restrict__ B, long long sB,
    u16* __restrict__ Cbf, float* __restrict__ Cf, long long sC,
    const float* __restrict__ bias_row,
    const float* __restrict__ bias_col,
    const float* __restrict__ residf, long long sR,
    int M, int N, int K)
{
  __shared__ u16 smem[18432];   // staging As[128][64]+Bs[128][64]=32KB; epilogue 4x[64][72]=36,864B
  u16* As = smem;
  u16* Bs = smem + 128*64;
  const int tid = threadIdx.x, w = tid>>6, lane = tid&63, col = lane&15, quad = lane>>4;
  const int m0 = blockIdx.y*128, n0 = blockIdx.x*128;
  const int lr8 = lane>>3;                       // row within 8-row chunk
  const int gsw = ((lane&7) ^ lr8)*8;            // swizzled source granule (row&7 == lr8 here)
  const u16* Ag = A + (size_t)blockIdx.z*sA + (size_t)(m0 + w*32 + lr8)*K + gsw;
  const u16* Bg = B + (size_t)blockIdx.z*sB + (size_t)(n0 + w*32 + lr8)*K + gsw;
  u16* ldsA = As + (w*32)*64;   // wave-uniform base
  u16* ldsB = Bs + (w*32)*64;
  const int mw = (w&1)*64, nw = (w>>1)*64;
  const int csw = col&7;                         // fragment row swizzle key

  v4f acc[4][4];
  #pragma unroll
  for (int i=0;i<4;++i)
    #pragma unroll
    for (int j=0;j<4;++j) acc[i][j] = v4zero();

  for (int kt = 0; kt < K; kt += 64){
    #pragma unroll
    for (int p = 0; p < 4; ++p){
      gl_lds16(Ag + (size_t)(p*8)*K + kt, ldsA + p*512);
      gl_lds16(Bg + (size_t)(p*8)*K + kt, ldsB + p*512);
    }
    __syncthreads();
    #pragma unroll
    for (int kh = 0; kh < 2; ++kh){
      const int fs = ((kh*4 + quad) ^ csw)*8;
      v8bf a[4], bb[4];
      #pragma unroll
      for (int i = 0; i < 4; ++i) a[i]  = *(const v8bf*)(As + (mw+i*16+col)*64 + fs);
      #pragma unroll
      for (int j = 0; j < 4; ++j) bb[j] = *(const v8bf*)(Bs + (nw+j*16+col)*64 + fs);
      #pragma unroll
      for (int i = 0; i < 4; ++i)
        #pragma unroll
        for (int j = 0; j < 4; ++j)
          acc[i][j] = MFMA16(a[i], bb[j], acc[i][j]);
    }
    __syncthreads();
  }

  float br[4][4], bc[4];
  #pragma unroll
  for (int i = 0; i < 4; ++i)
    #pragma unroll
    for (int r = 0; r < 4; ++r)
      br[i][r] = bias_row ? bias_row[m0+mw+i*16+quad*4+r] : 0.f;
  #pragma unroll
  for (int j = 0; j < 4; ++j)
    bc[j] = bias_col ? bias_col[n0+nw+j*16+col] : 0.f;

  if (Cf){
    float* Cb = Cf + (size_t)blockIdx.z*sC;
    const float* Rb = residf ? residf + (size_t)blockIdx.z*sR : nullptr;
    #pragma unroll
    for (int i = 0; i < 4; ++i)
      #pragma unroll
      for (int r = 0; r < 4; ++r){
        int row = m0+mw+i*16+quad*4+r;
        #pragma unroll
        for (int j = 0; j < 4; ++j){
          size_t goff = (size_t)row*N + n0+nw+j*16+col;
          float val = acc[i][j][r] + br[i][r] + bc[j];
          if (Rb) val += Rb[goff];
          Cb[goff] = val;
        }
      }
  } else {
    u16* Cs = smem + w*(64*72);
    #pragma unroll
    for (int i = 0; i < 4; ++i)
      #pragma unroll
      for (int j = 0; j < 4; ++j)
        #pragma unroll
        for (int r = 0; r < 4; ++r)
          Cs[(i*16+quad*4+r)*72 + j*16+col] = f2bf(acc[i][j][r] + br[i][r] + bc[j]);
    __syncthreads();
    u16* Cb = Cbf + (size_t)blockIdx.z*sC;
    #pragma unroll
    for (int p = 0; p < 8; ++p){
      int rl = p*8 + (lane>>3), cl = (lane&7)*8;
      size_t goff = (size_t)(m0+mw+rl)*N + n0+nw+cl;
      *(int4*)(Cb + goff) = *(int4*)(Cs + rl*72 + cl);
    }
  }
}

// ============ Fused flash attention (round-2 structure + swizzled/aliased LDS + exp2) ============
// qk[b][n][0..511]=q, [512..1023]=k; vv[b][c_all][m]; out[b][n][c_all]
// flat grid 512: qt = id>>6, bh = id&63 -> same-(b,h) blocks land on same XCD.
// LDS 32,768 B: KP = Ks[64][128] aliased with Ps[128][64]; Vs[128][64].
// XOR-swizzled on 8-u16 granules: slot s of row r holds global granule s^(r&7).
__global__ __launch_bounds__(256,2) void attn_kernel(const u16* __restrict__ qk, const u16* __restrict__ vv,
                                                     u16* __restrict__ outp){
  __shared__ u16 smem[16384];
  u16* KP = smem;               // Ks [64][128] / Ps [128][64] (aliased)
  u16* Vs = smem + 8192;        // [128][64]
  const int id = blockIdx.x;
  const int qt = id >> 6, bh = id & 63, b = bh >> 2, h = bh & 3;
  const int n0 = qt*128;
  const int tid = threadIdx.x, w = tid>>6, lane = tid&63, col = lane&15, quad = lane>>4;
  const size_t bq = (size_t)b*1024*1024;
  const float scale2 = 0.12751742f;  // (1/sqrt(128)) * log2(e)

  // Q fragments in registers for the whole kernel (A-operand layout)
  v8bf aq[2][4];
  #pragma unroll
  for (int i = 0; i < 2; ++i)
    #pragma unroll
    for (int kk = 0; kk < 4; ++kk)
      aq[i][kk] = *(const v8bf*)(qk + bq + (size_t)(n0 + w*32 + i*16 + col)*1024 + h*128 + kk*32 + quad*8);

  v4f o[2][8];
  #pragma unroll
  for (int i=0;i<2;++i)
    #pragma unroll
    for (int j=0;j<8;++j) o[i][j] = v4zero();
  float mi[8], li[8];
  #pragma unroll
  for (int r=0;r<8;++r){ mi[r] = -1e30f; li[r] = 0.f; }

  for (int mt = 0; mt < 1024; mt += 64){
    #pragma unroll
    for (int p = 0; p < 4; ++p){
      int r = p*16 + (tid>>4);
      int gc = (tid&15) ^ (r&7);
      *(int4*)(KP + (r<<7) + (gc<<3)) =
        *(const int4*)(qk + bq + (size_t)(mt + r)*1024 + 512 + h*128 + ((tid&15)<<3));
    }
    #pragma unroll
    for (int p = 0; p < 4; ++p){
      int r = p*32 + (tid>>3);
      int gm = (tid&7) ^ (r&7);
      *(int4*)(Vs + (r<<6) + (gm<<3)) =
        *(const int4*)(vv + ((size_t)b*512 + h*128 + r)*1024 + mt + ((tid&7)<<3));
    }
    __syncthreads();                               // (A) staging visible

    // S = Q K^T (raw, unscaled)
    v4f s[2][4];
    #pragma unroll
    for (int i=0;i<2;++i)
      #pragma unroll
      for (int j=0;j<4;++j) s[i][j] = v4zero();
    #pragma unroll
    for (int kk = 0; kk < 4; ++kk){
      v8bf bk[4];
      #pragma unroll
      for (int j = 0; j < 4; ++j){
        int r = j*16 + col;
        int g = (kk*4 + quad) ^ (r&7);
        bk[j] = *(const v8bf*)(KP + (r<<7) + (g<<3));
      }
      #pragma unroll
      for (int i = 0; i < 2; ++i)
        #pragma unroll
        for (int j = 0; j < 4; ++j)
          s[i][j] = MFMA16(aq[i][kk], bk[j], s[i][j]);
    }
    __syncthreads();                               // (B) Ks reads done (KP becomes Ps)

    // online softmax in base-2 domain
    #pragma unroll
    for (int i = 0; i < 2; ++i)
      #pragma unroll
      for (int r = 0; r < 4; ++r){
        float mx = fmaxf(fmaxf(s[i][0][r], s[i][1][r]), fmaxf(s[i][2][r], s[i][3][r]));
        mx = fmaxf(mx, __shfl_xor(mx, 1));
        mx = fmaxf(mx, __shfl_xor(mx, 2));
        mx = fmaxf(mx, __shfl_xor(mx, 4));
        mx = fmaxf(mx, __shfl_xor(mx, 8));
        int ir = i*4 + r;
        float mnew  = fmaxf(mi[ir], mx*scale2);
        float alpha = exp2f(mi[ir] - mnew);
        mi[ir] = mnew;
        float rsum = 0.f;
        #pragma unroll
        for (int j = 0; j < 4; ++j){
          float pv = exp2f(fmaf(s[i][j][r], scale2, -mnew));
          s[i][j][r] = pv;
          rsum += pv;
        }
        rsum += __shfl_xor(rsum, 1);
        rsum += __shfl_xor(rsum, 2);
        rsum += __shfl_xor(rsum, 4);
        rsum += __shfl_xor(rsum, 8);
        li[ir] = li[ir]*alpha + rsum;
        #pragma unroll
        for (int j = 0; j < 8; ++j) o[i][j][r] *= alpha;
      }

    // P -> Ps (A-operand layout via LDS, swizzled)
    #pragma unroll
    for (int i = 0; i < 2; ++i)
      #pragma unroll
      for (int j = 0; j < 4; ++j)
        #pragma unroll
        for (int r = 0; r < 4; ++r){
          int rr = w*32 + i*16 + quad*4 + r;
          int m  = j*16 + col;
          KP[(rr<<6) + ((((m>>3) ^ (rr&7))<<3)) + (m&7)] = f2bf(s[i][j][r]);
        }
    __syncthreads();                               // (C) Ps visible

    // O += P V^T
    #pragma unroll
    for (int kk = 0; kk < 2; ++kk){
      v8bf ap[2];
      #pragma unroll
      for (int i = 0; i < 2; ++i){
        int rr = w*32 + i*16 + col;
        int g = (kk*4 + quad) ^ (rr&7);
        ap[i] = *(const v8bf*)(KP + (rr<<6) + (g<<3));
      }
      #pragma unroll
      for (int j = 0; j < 8; ++j){
        int vr = j*16 + col;
        int g = (kk*4 + quad) ^ (vr&7);
        v8bf bv = *(const v8bf*)(Vs + (vr<<6) + (g<<3));
        #pragma unroll
        for (int i = 0; i < 2; ++i) o[i][j] = MFMA16(ap[i], bv, o[i][j]);
      }
    }
    __syncthreads();                               // (D) PV done; safe to restage
  }

  #pragma unroll
  for (int i = 0; i < 2; ++i)
    #pragma unroll
    for (int r = 0; r < 4; ++r){
      float inv = 1.f / li[i*4+r];
      #pragma unroll
      for (int j = 0; j < 8; ++j) o[i][j][r] *= inv;
    }

  // bounce O through LDS (swizzled [128][128]) for coalesced 16B stores
  #pragma unroll
  for (int i = 0; i < 2; ++i)
    #pragma unroll
    for (int j = 0; j < 8; ++j)
      #pragma unroll
      for (int r = 0; r < 4; ++r){
        int rr = w*32 + i*16 + quad*4 + r;
        int c  = j*16 + col;
        smem[(rr<<7) + ((((c>>3) ^ (rr&7))<<3)) + (c&7)] = f2bf(o[i][j][r]);
      }
  __syncthreads();
  #pragma unroll
  for (int p = 0; p < 8; ++p){
    int nr = p*16 + (tid>>4);
    int gc = (tid&15) ^ (nr&7);
    *(int4*)(outp + ((size_t)b*1024 + n0 + nr)*512 + h*128 + ((tid&15)<<3)) =
      *(int4*)(smem + (nr<<7) + (gc<<3));
  }
}

extern "C" void kernel_launch(void* const* d_in, const int* in_sizes, int n_in,
                              void* d_out, int out_size, void* d_ws, size_t ws_size,
                              hipStream_t stream){
  const float* x      = (const float*)d_in[0];
  const float* norm_w = (const float*)d_in[1];
  const float* norm_b = (const float*)d_in[2];
  const float* qkv_w  = (const float*)d_in[3];
  const float* qkv_b  = (const float*)d_in[4];
  const float* proj_w = (const float*)d_in[5];
  const float* proj_b = (const float*)d_in[6];
  float* out = (float*)d_out;

  u16* h_t   = (u16*)d_ws;                                  // [16][1024][512]
  u16* qk_t  = h_t  + (size_t)16*1024*512;                  // [16][1024][1024]
  u16* v_ws  = qk_t + (size_t)16*1024*1024;                 // [16][512][1024]
  u16* wq_bf = v_ws + (size_t)16*512*1024;                  // [1536][512]
  u16* wp_bf = wq_bf + (size_t)1536*512;                    // [512][512]
  float* stats = (float*)(wp_bf + (size_t)512*512);         // [512][2]
  u16* attnout = h_t;                                       // reuse

  cvt_kernel<<<768, 256, 0, stream>>>(qkv_w, wq_bf, 1536*512);
  cvt_kernel<<<256, 256, 0, stream>>>(proj_w, wp_bf, 512*512);
  gn_stats_kernel<<<512, 256, 0, stream>>>(x, stats);
  gn_apply_kernel<<<dim3(32,16), 256, 0, stream>>>(x, norm_w, norm_b, stats, h_t);

  gemm_bt_kernel<<<dim3(8,8,16), 256, 0, stream>>>(
      h_t, (long long)1024*512, wq_bf, 0,
      qk_t, nullptr, (long long)1024*1024, nullptr, qkv_b, nullptr, 0, 1024, 1024, 512);

  gemm_bt_kernel<<<dim3(8,4,16), 256, 0, stream>>>(
      wq_bf + (size_t)1024*512, 0, h_t, (long long)1024*512,
      v_ws, nullptr, (long long)512*1024, qkv_b + 1024, nullptr, nullptr, 0, 512, 1024, 512);

  attn_kernel<<<512, 256, 0, stream>>>(qk_t, v_ws, attnout);

  gemm_bt_kernel<<<dim3(8,4,16), 256, 0, stream>>>(
      wp_bf, 0, attnout, (long long)1024*512,
      nullptr, out, (long long)512*1024, proj_b, nullptr, x, (long long)512*1024, 512, 1024, 512);
}

// Round 6
// 221.305 us; speedup vs baseline: 2.3458x; 1.2270x over previous
//
#include <hip/hip_runtime.h>

typedef __bf16 v8bf __attribute__((ext_vector_type(8)));
typedef float  v4f  __attribute__((ext_vector_type(4)));
typedef unsigned short u16;

__device__ __forceinline__ u16 f2bf(float f){
  __bf16 h = (__bf16)f;
  union { __bf16 h; u16 u; } c; c.h = h; return c.u;
}
__device__ __forceinline__ v4f v4zero(){ v4f z; z[0]=0.f; z[1]=0.f; z[2]=0.f; z[3]=0.f; return z; }

#define MFMA16(a,b,c) __builtin_amdgcn_mfma_f32_16x16x32_bf16((a),(b),(c),0,0,0)

// async global->LDS, 16B per lane; LDS dest = wave-uniform base + lane*16
__device__ __forceinline__ void gl_lds16(const u16* g, u16* l){
  __builtin_amdgcn_global_load_lds((const __attribute__((address_space(1))) void*)g,
                                   (__attribute__((address_space(3))) void*)l, 16, 0, 0);
}

// ============ f32 -> bf16 bulk convert ============
__global__ __launch_bounds__(256) void cvt_kernel(const float* __restrict__ src, u16* __restrict__ dst, int n){
  int i = (blockIdx.x*256 + threadIdx.x)*4;
  if (i < n){
    float4 v = *(const float4*)(src + i);
    ushort4 o;
    o.x = f2bf(v.x); o.y = f2bf(v.y); o.z = f2bf(v.z); o.w = f2bf(v.w);
    *(ushort4*)(dst + i) = o;
  }
}

// ============ GroupNorm stats: one block per (b,g) ============
__global__ __launch_bounds__(256) void gn_stats_kernel(const float* __restrict__ x, float* __restrict__ stats){
  const float* base = x + (size_t)blockIdx.x * 16384;
  float s = 0.f, ss = 0.f;
  #pragma unroll
  for (int it = 0; it < 16; ++it){
    float4 v = *(const float4*)(base + it*1024 + threadIdx.x*4);
    s  += v.x + v.y + v.z + v.w;
    ss += v.x*v.x + v.y*v.y + v.z*v.z + v.w*v.w;
  }
  #pragma unroll
  for (int off = 32; off > 0; off >>= 1){ s += __shfl_down(s, off); ss += __shfl_down(ss, off); }
  __shared__ float red[8];
  int w = threadIdx.x >> 6;
  if ((threadIdx.x & 63) == 0){ red[w] = s; red[4+w] = ss; }
  __syncthreads();
  if (threadIdx.x == 0){
    float S  = red[0]+red[1]+red[2]+red[3];
    float SS = red[4]+red[5]+red[6]+red[7];
    float mean = S * (1.f/16384.f);
    float var  = SS * (1.f/16384.f) - mean*mean;
    stats[blockIdx.x*2]   = mean;
    stats[blockIdx.x*2+1] = rsqrtf(var + 1e-5f);
  }
}

// ============ GroupNorm apply + transpose: f32 x -> bf16 h_t[b][n][c] ============
__global__ __launch_bounds__(256) void gn_apply_kernel(const float* __restrict__ x, const float* __restrict__ nw,
                                                       const float* __restrict__ nb, const float* __restrict__ stats,
                                                       u16* __restrict__ h_t){
  __shared__ u16 tile[32*520];   // [n_local 32][c 512 + pad 8]
  int b = blockIdx.y, n0 = blockIdx.x*32, tid = threadIdx.x;
  int cr = tid >> 2, nn = (tid & 3)*8;
  #pragma unroll
  for (int p = 0; p < 8; ++p){
    int c = p*64 + cr;
    const float* px = x + (size_t)(b*512 + c)*1024 + n0 + nn;
    float4 u0 = *(const float4*)(px);
    float4 u1 = *(const float4*)(px + 4);
    int g = c >> 4;
    float mean = stats[(b*32+g)*2], rstd = stats[(b*32+g)*2+1];
    float wv = nw[c], bv = nb[c];
    float vals[8] = {u0.x,u0.y,u0.z,u0.w,u1.x,u1.y,u1.z,u1.w};
    #pragma unroll
    for (int e = 0; e < 8; ++e)
      tile[(nn+e)*520 + c] = f2bf((vals[e] - mean)*rstd*wv + bv);
  }
  __syncthreads();
  #pragma unroll
  for (int p = 0; p < 8; ++p){
    int n  = p*4 + (tid >> 6);
    int c0 = (tid & 63)*8;
    *(int4*)(h_t + ((size_t)b*1024 + n0 + n)*512 + c0) = *(int4*)(tile + n*520 + c0);
  }
}

// ============ Generic bf16 GEMM: C[M][N] = A[M][K]*B[N][K]^T, BK=64 ============
// global_load_lds staging; XOR-granule swizzle folded into SOURCE addresses so
// fragment ds_read_b128s hit all 32 banks (2-way = free).
// grid (N/128, M/128, batch), 256 threads (4 waves, each 64x64)
__global__ __launch_bounds__(256,2) void gemm_bt_kernel(
    const u16* __restrict__ A, long long sA,
    const u16* __restrict__ B, long long sB,
    u16* __restrict__ Cbf, float* __restrict__ Cf, long long sC,
    const float* __restrict__ bias_row,
    const float* __restrict__ bias_col,
    const float* __restrict__ residf, long long sR,
    int M, int N, int K)
{
  __shared__ u16 smem[18432];   // staging As[128][64]+Bs[128][64]=32KB; epilogue 4x[64][72]=36,864B
  u16* As = smem;
  u16* Bs = smem + 128*64;
  const int tid = threadIdx.x, w = tid>>6, lane = tid&63, col = lane&15, quad = lane>>4;
  const int m0 = blockIdx.y*128, n0 = blockIdx.x*128;
  const int lr8 = lane>>3;
  const int gsw = ((lane&7) ^ lr8)*8;
  const u16* Ag = A + (size_t)blockIdx.z*sA + (size_t)(m0 + w*32 + lr8)*K + gsw;
  const u16* Bg = B + (size_t)blockIdx.z*sB + (size_t)(n0 + w*32 + lr8)*K + gsw;
  u16* ldsA = As + (w*32)*64;
  u16* ldsB = Bs + (w*32)*64;
  const int mw = (w&1)*64, nw = (w>>1)*64;
  const int csw = col&7;

  v4f acc[4][4];
  #pragma unroll
  for (int i=0;i<4;++i)
    #pragma unroll
    for (int j=0;j<4;++j) acc[i][j] = v4zero();

  for (int kt = 0; kt < K; kt += 64){
    #pragma unroll
    for (int p = 0; p < 4; ++p){
      gl_lds16(Ag + (size_t)(p*8)*K + kt, ldsA + p*512);
      gl_lds16(Bg + (size_t)(p*8)*K + kt, ldsB + p*512);
    }
    __syncthreads();
    #pragma unroll
    for (int kh = 0; kh < 2; ++kh){
      const int fs = ((kh*4 + quad) ^ csw)*8;
      v8bf a[4], bb[4];
      #pragma unroll
      for (int i = 0; i < 4; ++i) a[i]  = *(const v8bf*)(As + (mw+i*16+col)*64 + fs);
      #pragma unroll
      for (int j = 0; j < 4; ++j) bb[j] = *(const v8bf*)(Bs + (nw+j*16+col)*64 + fs);
      #pragma unroll
      for (int i = 0; i < 4; ++i)
        #pragma unroll
        for (int j = 0; j < 4; ++j)
          acc[i][j] = MFMA16(a[i], bb[j], acc[i][j]);
    }
    __syncthreads();
  }

  float br[4][4], bc[4];
  #pragma unroll
  for (int i = 0; i < 4; ++i)
    #pragma unroll
    for (int r = 0; r < 4; ++r)
      br[i][r] = bias_row ? bias_row[m0+mw+i*16+quad*4+r] : 0.f;
  #pragma unroll
  for (int j = 0; j < 4; ++j)
    bc[j] = bias_col ? bias_col[n0+nw+j*16+col] : 0.f;

  if (Cf){
    float* Cb = Cf + (size_t)blockIdx.z*sC;
    const float* Rb = residf ? residf + (size_t)blockIdx.z*sR : nullptr;
    #pragma unroll
    for (int i = 0; i < 4; ++i)
      #pragma unroll
      for (int r = 0; r < 4; ++r){
        int row = m0+mw+i*16+quad*4+r;
        #pragma unroll
        for (int j = 0; j < 4; ++j){
          size_t goff = (size_t)row*N + n0+nw+j*16+col;
          float val = acc[i][j][r] + br[i][r] + bc[j];
          if (Rb) val += Rb[goff];
          Cb[goff] = val;
        }
      }
  } else {
    u16* Cs = smem + w*(64*72);
    #pragma unroll
    for (int i = 0; i < 4; ++i)
      #pragma unroll
      for (int j = 0; j < 4; ++j)
        #pragma unroll
        for (int r = 0; r < 4; ++r)
          Cs[(i*16+quad*4+r)*72 + j*16+col] = f2bf(acc[i][j][r] + br[i][r] + bc[j]);
    __syncthreads();
    u16* Cb = Cbf + (size_t)blockIdx.z*sC;
    #pragma unroll
    for (int p = 0; p < 8; ++p){
      int rl = p*8 + (lane>>3), cl = (lane&7)*8;
      size_t goff = (size_t)(m0+mw+rl)*N + n0+nw+cl;
      *(int4*)(Cb + goff) = *(int4*)(Cs + rl*72 + cl);
    }
  }
}

// ============ Fused flash attention, no-max softmax, ones-column row-sum ============
// qk[b][n][0..511]=q, [512..1023]=k; vv[b][c_all][m]; out[b][n][c_all]
// flat grid 512: qt=id>>6, bh=id&63 -> same-(b,h) blocks on same XCD.
// LDS 51,200 B: Ks[64][128] + Vs[144][64] (rows 128..143 = ones col) + Ps[128][64].
// Ks/Vs: slot s of row r holds granule s^(r&7) (staged via swizzled gl_lds16 sources).
// Ps: slot key (rr^(rr>>3))&7. P is wave-private -> no barrier between P write and PV read.
// 2 barriers per K-tile: post-staging, post-PV.
__global__ __launch_bounds__(256,2) void attn_kernel(const u16* __restrict__ qk, const u16* __restrict__ vv,
                                                     u16* __restrict__ outp){
  __shared__ u16 smem[25600];
  u16* Ks = smem;                  // [64][128]
  u16* Vs = smem + 8192;           // [144][64]
  u16* Ps = smem + 8192 + 9216;    // [128][64]
  const int id = blockIdx.x;
  const int qt = id >> 6, bh = id & 63, b = bh >> 2, h = bh & 3;
  const int n0 = qt*128;
  const int tid = threadIdx.x, w = tid>>6, lane = tid&63, col = lane&15, quad = lane>>4;
  const size_t bq = (size_t)b*1024*1024;
  const float scale2 = 0.12751742f;  // (1/sqrt(128)) * log2(e)

  // ones-column rows of Vs (row 128 = 1.0, rows 129..143 = 0); visible after first barrier
  if (tid < 128){
    int r = 128 + (tid>>3);
    int pat = (r == 128) ? (int)0x3F803F80u : 0;
    int4 v; v.x = pat; v.y = pat; v.z = pat; v.w = pat;
    *(int4*)(Vs + r*64 + (tid&7)*8) = v;
  }

  // Q fragments in registers (A-operand layout)
  v8bf aq[2][4];
  #pragma unroll
  for (int i = 0; i < 2; ++i)
    #pragma unroll
    for (int kk = 0; kk < 4; ++kk)
      aq[i][kk] = *(const v8bf*)(qk + bq + (size_t)(n0 + w*32 + i*16 + col)*1024 + h*128 + kk*32 + quad*8);

  v4f o[2][9];
  #pragma unroll
  for (int i=0;i<2;++i)
    #pragma unroll
    for (int j=0;j<9;++j) o[i][j] = v4zero();

  // staging lane constants (swizzle folded into global source granule)
  const int krow = w*4 + (lane>>4);                 // LDS row within 16-row call-group offset
  const int kgr  = (lane&15) ^ (krow&7);
  const u16* kg_base = qk + bq + (size_t)krow*1024 + 512 + h*128 + kgr*8;
  u16* kl_base = Ks + (w*4)*128;
  const int vrow = w*8 + (lane>>3);
  const int vgr  = (lane&7) ^ (vrow&7);
  const u16* vg_base = vv + ((size_t)b*512 + h*128 + vrow)*1024 + vgr*8;
  u16* vl_base = Vs + (w*8)*64;

  for (int mt = 0; mt < 1024; mt += 64){
    #pragma unroll
    for (int p = 0; p < 4; ++p)
      gl_lds16(kg_base + (size_t)(mt + p*16)*1024, kl_base + p*16*128);
    #pragma unroll
    for (int p = 0; p < 4; ++p)
      gl_lds16(vg_base + (size_t)(p*32)*1024 + mt, vl_base + p*32*64);
    __syncthreads();                               // (A) staging visible

    // S = Q K^T (raw)
    v4f s[2][4];
    #pragma unroll
    for (int i=0;i<2;++i)
      #pragma unroll
      for (int j=0;j<4;++j) s[i][j] = v4zero();
    #pragma unroll
    for (int kk = 0; kk < 4; ++kk){
      v8bf bk[4];
      #pragma unroll
      for (int j = 0; j < 4; ++j){
        int r = j*16 + col;
        int g = (kk*4 + quad) ^ (r&7);
        bk[j] = *(const v8bf*)(Ks + (r<<7) + (g<<3));
      }
      #pragma unroll
      for (int i = 0; i < 2; ++i)
        #pragma unroll
        for (int j = 0; j < 4; ++j)
          s[i][j] = MFMA16(aq[i][kk], bk[j], s[i][j]);
    }

    // p = exp2(s*scale2) (no max subtraction; logits bounded), write to wave-private Ps
    #pragma unroll
    for (int i = 0; i < 2; ++i)
      #pragma unroll
      for (int j = 0; j < 4; ++j)
        #pragma unroll
        for (int r = 0; r < 4; ++r){
          int rr = w*32 + i*16 + quad*4 + r;
          int m  = j*16 + col;
          int key = (rr ^ (rr>>3)) & 7;
          Ps[(rr<<6) + ((((m>>3) ^ key))<<3) + (m&7)] = f2bf(exp2f(s[i][j][r]*scale2));
        }
    // wave-private write->read: only lgkmcnt needed (compiler inserts), no barrier

    // O += P [V; ones]^T
    #pragma unroll
    for (int kk = 0; kk < 2; ++kk){
      v8bf ap[2];
      #pragma unroll
      for (int i = 0; i < 2; ++i){
        int rr = w*32 + i*16 + col;
        int key = (rr ^ (rr>>3)) & 7;
        int g = (kk*4 + quad) ^ key;
        ap[i] = *(const v8bf*)(Ps + (rr<<6) + (g<<3));
      }
      #pragma unroll
      for (int j = 0; j < 9; ++j){
        int vr = j*16 + col;
        int g = (kk*4 + quad) ^ (vr&7);
        v8bf bv = *(const v8bf*)(Vs + (vr<<6) + (g<<3));
        #pragma unroll
        for (int i = 0; i < 2; ++i) o[i][j] = MFMA16(ap[i], bv, o[i][j]);
      }
    }
    __syncthreads();                               // (D) PV done; safe to restage
  }

  // l = row-sum lives in ones-column tile (col 0), broadcast within quad; normalize
  #pragma unroll
  for (int i = 0; i < 2; ++i)
    #pragma unroll
    for (int r = 0; r < 4; ++r){
      float l = __shfl(o[i][8][r], quad<<4);
      float inv = 1.f / l;
      #pragma unroll
      for (int j = 0; j < 8; ++j) o[i][j][r] *= inv;
    }

  // bounce O through LDS (swizzled [128][128]) for coalesced 16B stores
  #pragma unroll
  for (int i = 0; i < 2; ++i)
    #pragma unroll
    for (int j = 0; j < 8; ++j)
      #pragma unroll
      for (int r = 0; r < 4; ++r){
        int rr = w*32 + i*16 + quad*4 + r;
        int c  = j*16 + col;
        smem[(rr<<7) + ((((c>>3) ^ (rr&7))<<3)) + (c&7)] = f2bf(o[i][j][r]);
      }
  __syncthreads();
  #pragma unroll
  for (int p = 0; p < 8; ++p){
    int nr = p*16 + (tid>>4);
    int gc = (tid&15) ^ (nr&7);
    *(int4*)(outp + ((size_t)b*1024 + n0 + nr)*512 + h*128 + ((tid&15)<<3)) =
      *(int4*)(smem + (nr<<7) + (gc<<3));
  }
}

extern "C" void kernel_launch(void* const* d_in, const int* in_sizes, int n_in,
                              void* d_out, int out_size, void* d_ws, size_t ws_size,
                              hipStream_t stream){
  const float* x      = (const float*)d_in[0];
  const float* norm_w = (const float*)d_in[1];
  const float* norm_b = (const float*)d_in[2];
  const float* qkv_w  = (const float*)d_in[3];
  const float* qkv_b  = (const float*)d_in[4];
  const float* proj_w = (const float*)d_in[5];
  const float* proj_b = (const float*)d_in[6];
  float* out = (float*)d_out;

  u16* h_t   = (u16*)d_ws;                                  // [16][1024][512]
  u16* qk_t  = h_t  + (size_t)16*1024*512;                  // [16][1024][1024]
  u16* v_ws  = qk_t + (size_t)16*1024*1024;                 // [16][512][1024]
  u16* wq_bf = v_ws + (size_t)16*512*1024;                  // [1536][512]
  u16* wp_bf = wq_bf + (size_t)1536*512;                    // [512][512]
  float* stats = (float*)(wp_bf + (size_t)512*512);         // [512][2]
  u16* attnout = h_t;                                       // reuse

  cvt_kernel<<<768, 256, 0, stream>>>(qkv_w, wq_bf, 1536*512);
  cvt_kernel<<<256, 256, 0, stream>>>(proj_w, wp_bf, 512*512);
  gn_stats_kernel<<<512, 256, 0, stream>>>(x, stats);
  gn_apply_kernel<<<dim3(32,16), 256, 0, stream>>>(x, norm_w, norm_b, stats, h_t);

  gemm_bt_kernel<<<dim3(8,8,16), 256, 0, stream>>>(
      h_t, (long long)1024*512, wq_bf, 0,
      qk_t, nullptr, (long long)1024*1024, nullptr, qkv_b, nullptr, 0, 1024, 1024, 512);

  gemm_bt_kernel<<<dim3(8,4,16), 256, 0, stream>>>(
      wq_bf + (size_t)1024*512, 0, h_t, (long long)1024*512,
      v_ws, nullptr, (long long)512*1024, qkv_b + 1024, nullptr, nullptr, 0, 512, 1024, 512);

  attn_kernel<<<512, 256, 0, stream>>>(qk_t, v_ws, attnout);

  gemm_bt_kernel<<<dim3(8,4,16), 256, 0, stream>>>(
      wp_bf, 0, attnout, (long long)1024*512,
      nullptr, out, (long long)512*1024, proj_b, nullptr, x, (long long)512*1024, 512, 1024, 512);
}

// Round 7
// 218.849 us; speedup vs baseline: 2.3721x; 1.0112x over previous
//
#include <hip/hip_runtime.h>

typedef __bf16 v8bf __attribute__((ext_vector_type(8)));
typedef float  v4f  __attribute__((ext_vector_type(4)));
typedef unsigned short u16;

__device__ __forceinline__ u16 f2bf(float f){
  __bf16 h = (__bf16)f;
  union { __bf16 h; u16 u; } c; c.h = h; return c.u;
}
__device__ __forceinline__ v4f v4zero(){ v4f z; z[0]=0.f; z[1]=0.f; z[2]=0.f; z[3]=0.f; return z; }

#define MFMA16(a,b,c) __builtin_amdgcn_mfma_f32_16x16x32_bf16((a),(b),(c),0,0,0)

// async global->LDS, 16B per lane; LDS dest = wave-uniform base + lane*16
__device__ __forceinline__ void gl_lds16(const u16* g, u16* l){
  __builtin_amdgcn_global_load_lds((const __attribute__((address_space(1))) void*)g,
                                   (__attribute__((address_space(3))) void*)l, 16, 0, 0);
}

// ============ f32 -> bf16 bulk convert ============
__global__ __launch_bounds__(256) void cvt_kernel(const float* __restrict__ src, u16* __restrict__ dst, int n){
  int i = (blockIdx.x*256 + threadIdx.x)*4;
  if (i < n){
    float4 v = *(const float4*)(src + i);
    ushort4 o;
    o.x = f2bf(v.x); o.y = f2bf(v.y); o.z = f2bf(v.z); o.w = f2bf(v.w);
    *(ushort4*)(dst + i) = o;
  }
}

// ============ GroupNorm stats: one block per (b,g) ============
__global__ __launch_bounds__(256) void gn_stats_kernel(const float* __restrict__ x, float* __restrict__ stats){
  const float* base = x + (size_t)blockIdx.x * 16384;
  float s = 0.f, ss = 0.f;
  #pragma unroll
  for (int it = 0; it < 16; ++it){
    float4 v = *(const float4*)(base + it*1024 + threadIdx.x*4);
    s  += v.x + v.y + v.z + v.w;
    ss += v.x*v.x + v.y*v.y + v.z*v.z + v.w*v.w;
  }
  #pragma unroll
  for (int off = 32; off > 0; off >>= 1){ s += __shfl_down(s, off); ss += __shfl_down(ss, off); }
  __shared__ float red[8];
  int w = threadIdx.x >> 6;
  if ((threadIdx.x & 63) == 0){ red[w] = s; red[4+w] = ss; }
  __syncthreads();
  if (threadIdx.x == 0){
    float S  = red[0]+red[1]+red[2]+red[3];
    float SS = red[4]+red[5]+red[6]+red[7];
    float mean = S * (1.f/16384.f);
    float var  = SS * (1.f/16384.f) - mean*mean;
    stats[blockIdx.x*2]   = mean;
    stats[blockIdx.x*2+1] = rsqrtf(var + 1e-5f);
  }
}

// ============ GroupNorm apply + transpose: f32 x -> bf16 h_t[b][n][c] ============
__global__ __launch_bounds__(256) void gn_apply_kernel(const float* __restrict__ x, const float* __restrict__ nw,
                                                       const float* __restrict__ nb, const float* __restrict__ stats,
                                                       u16* __restrict__ h_t){
  __shared__ u16 tile[32*520];   // [n_local 32][c 512 + pad 8]
  int b = blockIdx.y, n0 = blockIdx.x*32, tid = threadIdx.x;
  int cr = tid >> 2, nn = (tid & 3)*8;
  #pragma unroll
  for (int p = 0; p < 8; ++p){
    int c = p*64 + cr;
    const float* px = x + (size_t)(b*512 + c)*1024 + n0 + nn;
    float4 u0 = *(const float4*)(px);
    float4 u1 = *(const float4*)(px + 4);
    int g = c >> 4;
    float mean = stats[(b*32+g)*2], rstd = stats[(b*32+g)*2+1];
    float wv = nw[c], bv = nb[c];
    float vals[8] = {u0.x,u0.y,u0.z,u0.w,u1.x,u1.y,u1.z,u1.w};
    #pragma unroll
    for (int e = 0; e < 8; ++e)
      tile[(nn+e)*520 + c] = f2bf((vals[e] - mean)*rstd*wv + bv);
  }
  __syncthreads();
  #pragma unroll
  for (int p = 0; p < 8; ++p){
    int n  = p*4 + (tid >> 6);
    int c0 = (tid & 63)*8;
    *(int4*)(h_t + ((size_t)b*1024 + n0 + n)*512 + c0) = *(int4*)(tile + n*520 + c0);
  }
}

// ============ Fused QKV GEMM: C[n][o] = h_t[b][n][:] . wq[o][:] + qkv_b[o] ============
// Block tile 128(n) x 256(o), 4 waves each 64x128 (acc[4][8]), BK=64.
// o-tiles < 1024 -> qk_t[b][n][o]; o-tiles >= 1024 -> v_ws[b][o-1024][n] (transposed bounce).
// Swizzled global_load_lds staging: slot s of row r holds granule s^(r&7).
// grid (6, 8, 16).
__global__ __launch_bounds__(256,2) void gemm_qkv_kernel(
    const u16* __restrict__ A,       // h_t  [16][1024][512]
    const u16* __restrict__ B,       // wq_bf [1536][512]
    const float* __restrict__ bias,  // qkv_b [1536] f32
    u16* __restrict__ qk_t, u16* __restrict__ v_ws)
{
  __shared__ u16 smem[24576];    // 49,152 B: As[128][64]=16KB + Bs[256][64]=32KB; epilogue reuses
  u16* As = smem;
  u16* Bs = smem + 128*64;
  const int tid = threadIdx.x, w = tid>>6, lane = tid&63, col = lane&15, quad = lane>>4;
  const int m0 = blockIdx.y*128;       // n
  const int n0 = blockIdx.x*256;       // o
  const int b  = blockIdx.z;
  const int lr8 = lane>>3;
  const int gsw = ((lane&7) ^ lr8)*8;
  const u16* Ag = A + ((size_t)b*1024 + m0 + w*32 + lr8)*512 + gsw;
  const u16* Bg = B + (size_t)(n0 + w*64 + lr8)*512 + gsw;
  u16* ldsA = As + (w*32)*64;
  u16* ldsB = Bs + (w*64)*64;
  const int mw = (w&1)*64, nw = (w>>1)*128;
  const int csw = col&7;

  v4f acc[4][8];
  #pragma unroll
  for (int i=0;i<4;++i)
    #pragma unroll
    for (int j=0;j<8;++j) acc[i][j] = v4zero();

  for (int kt = 0; kt < 512; kt += 64){
    #pragma unroll
    for (int p = 0; p < 4; ++p)
      gl_lds16(Ag + (size_t)(p*8)*512 + kt, ldsA + p*512);
    #pragma unroll
    for (int p = 0; p < 8; ++p)
      gl_lds16(Bg + (size_t)(p*8)*512 + kt, ldsB + p*512);
    __syncthreads();
    #pragma unroll
    for (int kh = 0; kh < 2; ++kh){
      const int fs = ((kh*4 + quad) ^ csw)*8;
      v8bf a[4], bb[8];
      #pragma unroll
      for (int i = 0; i < 4; ++i) a[i]  = *(const v8bf*)(As + (mw+i*16+col)*64 + fs);
      #pragma unroll
      for (int j = 0; j < 8; ++j) bb[j] = *(const v8bf*)(Bs + (nw+j*16+col)*64 + fs);
      #pragma unroll
      for (int i = 0; i < 4; ++i)
        #pragma unroll
        for (int j = 0; j < 8; ++j)
          acc[i][j] = MFMA16(a[i], bb[j], acc[i][j]);
    }
    __syncthreads();
  }

  float bc[8];
  #pragma unroll
  for (int j = 0; j < 8; ++j)
    bc[j] = bias[n0 + nw + j*16 + col];

  if (n0 < 1024){
    // q|k: C[n][o] -> qk_t[b][n][o], per-wave [64][72] bounce in two 64-col halves (wave-private)
    u16* Cs = smem + w*(64*72);
    #pragma unroll
    for (int half = 0; half < 2; ++half){
      #pragma unroll
      for (int i = 0; i < 4; ++i)
        #pragma unroll
        for (int jj = 0; jj < 4; ++jj)
          #pragma unroll
          for (int r = 0; r < 4; ++r)
            Cs[(i*16+quad*4+r)*72 + jj*16+col] = f2bf(acc[i][half*4+jj][r] + bc[half*4+jj]);
      u16* dst = qk_t + (size_t)b*1024*1024;
      #pragma unroll
      for (int p = 0; p < 8; ++p){
        int rl = p*8 + (lane>>3), cl = (lane&7)*8;
        *(int4*)(dst + (size_t)(m0+mw+rl)*1024 + n0+nw+half*64+cl) = *(int4*)(Cs + rl*72 + cl);
      }
    }
  } else {
    // v: C[n][o] transposed -> v_ws[b][o-1024][n], per-wave [64][80] bounce (16B-aligned rows)
    u16* Ct = smem + w*(64*80);
    #pragma unroll
    for (int half = 0; half < 2; ++half){
      #pragma unroll
      for (int i = 0; i < 4; ++i)
        #pragma unroll
        for (int jj = 0; jj < 4; ++jj)
          #pragma unroll
          for (int r = 0; r < 4; ++r)
            Ct[(jj*16+col)*80 + i*16+quad*4+r] = f2bf(acc[i][half*4+jj][r] + bc[half*4+jj]);
      u16* dst = v_ws + (size_t)b*512*1024;
      #pragma unroll
      for (int p = 0; p < 8; ++p){
        int rl = p*8 + (lane>>3), cl = (lane&7)*8;
        *(int4*)(dst + (size_t)(n0-1024 + nw + half*64 + rl)*1024 + m0+mw+cl) = *(int4*)(Ct + rl*80 + cl);
      }
    }
  }
}

// ============ Generic bf16 GEMM (used for proj): C[M][N] = A[M][K]*B[N][K]^T, BK=64 ============
__global__ __launch_bounds__(256,2) void gemm_bt_kernel(
    const u16* __restrict__ A, long long sA,
    const u16* __restrict__ B, long long sB,
    u16* __restrict__ Cbf, float* __restrict__ Cf, long long sC,
    const float* __restrict__ bias_row,
    const float* __restrict__ bias_col,
    const float* __restrict__ residf, long long sR,
    int M, int N, int K)
{
  __shared__ u16 smem[18432];   // staging As[128][64]+Bs[128][64]=32KB; epilogue 4x[64][72]
  u16* As = smem;
  u16* Bs = smem + 128*64;
  const int tid = threadIdx.x, w = tid>>6, lane = tid&63, col = lane&15, quad = lane>>4;
  const int m0 = blockIdx.y*128, n0 = blockIdx.x*128;
  const int lr8 = lane>>3;
  const int gsw = ((lane&7) ^ lr8)*8;
  const u16* Ag = A + (size_t)blockIdx.z*sA + (size_t)(m0 + w*32 + lr8)*K + gsw;
  const u16* Bg = B + (size_t)blockIdx.z*sB + (size_t)(n0 + w*32 + lr8)*K + gsw;
  u16* ldsA = As + (w*32)*64;
  u16* ldsB = Bs + (w*32)*64;
  const int mw = (w&1)*64, nw = (w>>1)*64;
  const int csw = col&7;

  v4f acc[4][4];
  #pragma unroll
  for (int i=0;i<4;++i)
    #pragma unroll
    for (int j=0;j<4;++j) acc[i][j] = v4zero();

  for (int kt = 0; kt < K; kt += 64){
    #pragma unroll
    for (int p = 0; p < 4; ++p){
      gl_lds16(Ag + (size_t)(p*8)*K + kt, ldsA + p*512);
      gl_lds16(Bg + (size_t)(p*8)*K + kt, ldsB + p*512);
    }
    __syncthreads();
    #pragma unroll
    for (int kh = 0; kh < 2; ++kh){
      const int fs = ((kh*4 + quad) ^ csw)*8;
      v8bf a[4], bb[4];
      #pragma unroll
      for (int i = 0; i < 4; ++i) a[i]  = *(const v8bf*)(As + (mw+i*16+col)*64 + fs);
      #pragma unroll
      for (int j = 0; j < 4; ++j) bb[j] = *(const v8bf*)(Bs + (nw+j*16+col)*64 + fs);
      #pragma unroll
      for (int i = 0; i < 4; ++i)
        #pragma unroll
        for (int j = 0; j < 4; ++j)
          acc[i][j] = MFMA16(a[i], bb[j], acc[i][j]);
    }
    __syncthreads();
  }

  float br[4][4], bc[4];
  #pragma unroll
  for (int i = 0; i < 4; ++i)
    #pragma unroll
    for (int r = 0; r < 4; ++r)
      br[i][r] = bias_row ? bias_row[m0+mw+i*16+quad*4+r] : 0.f;
  #pragma unroll
  for (int j = 0; j < 4; ++j)
    bc[j] = bias_col ? bias_col[n0+nw+j*16+col] : 0.f;

  if (Cf){
    float* Cb = Cf + (size_t)blockIdx.z*sC;
    const float* Rb = residf ? residf + (size_t)blockIdx.z*sR : nullptr;
    #pragma unroll
    for (int i = 0; i < 4; ++i)
      #pragma unroll
      for (int r = 0; r < 4; ++r){
        int row = m0+mw+i*16+quad*4+r;
        #pragma unroll
        for (int j = 0; j < 4; ++j){
          size_t goff = (size_t)row*N + n0+nw+j*16+col;
          float val = acc[i][j][r] + br[i][r] + bc[j];
          if (Rb) val += Rb[goff];
          Cb[goff] = val;
        }
      }
  } else {
    u16* Cs = smem + w*(64*72);
    #pragma unroll
    for (int i = 0; i < 4; ++i)
      #pragma unroll
      for (int j = 0; j < 4; ++j)
        #pragma unroll
        for (int r = 0; r < 4; ++r)
          Cs[(i*16+quad*4+r)*72 + j*16+col] = f2bf(acc[i][j][r] + br[i][r] + bc[j]);
    __syncthreads();
    u16* Cb = Cbf + (size_t)blockIdx.z*sC;
    #pragma unroll
    for (int p = 0; p < 8; ++p){
      int rl = p*8 + (lane>>3), cl = (lane&7)*8;
      size_t goff = (size_t)(m0+mw+rl)*N + n0+nw+cl;
      *(int4*)(Cb + goff) = *(int4*)(Cs + rl*72 + cl);
    }
  }
}

// ============ Fused flash attention, no-max softmax, ones-column row-sum ============
// qk[b][n][0..511]=q, [512..1023]=k; vv[b][c_all][m]; out[b][n][c_all]
// flat grid 512: qt=id>>6, bh=id&63 -> same-(b,h) blocks on same XCD.
// LDS 51,200 B: Ks[64][128] + Vs[144][64] (rows 128..143 = ones col) + Ps[128][64].
// Ks/Vs: slot s of row r holds granule s^(r&7) (staged via swizzled gl_lds16 sources).
// Ps: slot key (rr^(rr>>3))&7. P is wave-private -> no barrier between P write and PV read.
__global__ __launch_bounds__(256,2) void attn_kernel(const u16* __restrict__ qk, const u16* __restrict__ vv,
                                                     u16* __restrict__ outp){
  __shared__ u16 smem[25600];
  u16* Ks = smem;                  // [64][128]
  u16* Vs = smem + 8192;           // [144][64]
  u16* Ps = smem + 8192 + 9216;    // [128][64]
  const int id = blockIdx.x;
  const int qt = id >> 6, bh = id & 63, b = bh >> 2, h = bh & 3;
  const int n0 = qt*128;
  const int tid = threadIdx.x, w = tid>>6, lane = tid&63, col = lane&15, quad = lane>>4;
  const size_t bq = (size_t)b*1024*1024;
  const float scale2 = 0.12751742f;  // (1/sqrt(128)) * log2(e)

  if (tid < 128){
    int r = 128 + (tid>>3);
    int pat = (r == 128) ? (int)0x3F803F80u : 0;
    int4 v; v.x = pat; v.y = pat; v.z = pat; v.w = pat;
    *(int4*)(Vs + r*64 + (tid&7)*8) = v;
  }

  v8bf aq[2][4];
  #pragma unroll
  for (int i = 0; i < 2; ++i)
    #pragma unroll
    for (int kk = 0; kk < 4; ++kk)
      aq[i][kk] = *(const v8bf*)(qk + bq + (size_t)(n0 + w*32 + i*16 + col)*1024 + h*128 + kk*32 + quad*8);

  v4f o[2][9];
  #pragma unroll
  for (int i=0;i<2;++i)
    #pragma unroll
    for (int j=0;j<9;++j) o[i][j] = v4zero();

  const int krow = w*4 + (lane>>4);
  const int kgr  = (lane&15) ^ (krow&7);
  const u16* kg_base = qk + bq + (size_t)krow*1024 + 512 + h*128 + kgr*8;
  u16* kl_base = Ks + (w*4)*128;
  const int vrow = w*8 + (lane>>3);
  const int vgr  = (lane&7) ^ (vrow&7);
  const u16* vg_base = vv + ((size_t)b*512 + h*128 + vrow)*1024 + vgr*8;
  u16* vl_base = Vs + (w*8)*64;

  for (int mt = 0; mt < 1024; mt += 64){
    #pragma unroll
    for (int p = 0; p < 4; ++p)
      gl_lds16(kg_base + (size_t)(mt + p*16)*1024, kl_base + p*16*128);
    #pragma unroll
    for (int p = 0; p < 4; ++p)
      gl_lds16(vg_base + (size_t)(p*32)*1024 + mt, vl_base + p*32*64);
    __syncthreads();                               // (A) staging visible

    v4f s[2][4];
    #pragma unroll
    for (int i=0;i<2;++i)
      #pragma unroll
      for (int j=0;j<4;++j) s[i][j] = v4zero();
    #pragma unroll
    for (int kk = 0; kk < 4; ++kk){
      v8bf bk[4];
      #pragma unroll
      for (int j = 0; j < 4; ++j){
        int r = j*16 + col;
        int g = (kk*4 + quad) ^ (r&7);
        bk[j] = *(const v8bf*)(Ks + (r<<7) + (g<<3));
      }
      #pragma unroll
      for (int i = 0; i < 2; ++i)
        #pragma unroll
        for (int j = 0; j < 4; ++j)
          s[i][j] = MFMA16(aq[i][kk], bk[j], s[i][j]);
    }

    #pragma unroll
    for (int i = 0; i < 2; ++i)
      #pragma unroll
      for (int j = 0; j < 4; ++j)
        #pragma unroll
        for (int r = 0; r < 4; ++r){
          int rr = w*32 + i*16 + quad*4 + r;
          int m  = j*16 + col;
          int key = (rr ^ (rr>>3)) & 7;
          Ps[(rr<<6) + ((((m>>3) ^ key))<<3) + (m&7)] = f2bf(exp2f(s[i][j][r]*scale2));
        }

    #pragma unroll
    for (int kk = 0; kk < 2; ++kk){
      v8bf ap[2];
      #pragma unroll
      for (int i = 0; i < 2; ++i){
        int rr = w*32 + i*16 + col;
        int key = (rr ^ (rr>>3)) & 7;
        int g = (kk*4 + quad) ^ key;
        ap[i] = *(const v8bf*)(Ps + (rr<<6) + (g<<3));
      }
      #pragma unroll
      for (int j = 0; j < 9; ++j){
        int vr = j*16 + col;
        int g = (kk*4 + quad) ^ (vr&7);
        v8bf bv = *(const v8bf*)(Vs + (vr<<6) + (g<<3));
        #pragma unroll
        for (int i = 0; i < 2; ++i) o[i][j] = MFMA16(ap[i], bv, o[i][j]);
      }
    }
    __syncthreads();                               // (D) PV done; safe to restage
  }

  #pragma unroll
  for (int i = 0; i < 2; ++i)
    #pragma unroll
    for (int r = 0; r < 4; ++r){
      float l = __shfl(o[i][8][r], quad<<4);
      float inv = 1.f / l;
      #pragma unroll
      for (int j = 0; j < 8; ++j) o[i][j][r] *= inv;
    }

  #pragma unroll
  for (int i = 0; i < 2; ++i)
    #pragma unroll
    for (int j = 0; j < 8; ++j)
      #pragma unroll
      for (int r = 0; r < 4; ++r){
        int rr = w*32 + i*16 + quad*4 + r;
        int c  = j*16 + col;
        smem[(rr<<7) + ((((c>>3) ^ (rr&7))<<3)) + (c&7)] = f2bf(o[i][j][r]);
      }
  __syncthreads();
  #pragma unroll
  for (int p = 0; p < 8; ++p){
    int nr = p*16 + (tid>>4);
    int gc = (tid&15) ^ (nr&7);
    *(int4*)(outp + ((size_t)b*1024 + n0 + nr)*512 + h*128 + ((tid&15)<<3)) =
      *(int4*)(smem + (nr<<7) + (gc<<3));
  }
}

extern "C" void kernel_launch(void* const* d_in, const int* in_sizes, int n_in,
                              void* d_out, int out_size, void* d_ws, size_t ws_size,
                              hipStream_t stream){
  const float* x      = (const float*)d_in[0];
  const float* norm_w = (const float*)d_in[1];
  const float* norm_b = (const float*)d_in[2];
  const float* qkv_w  = (const float*)d_in[3];
  const float* qkv_b  = (const float*)d_in[4];
  const float* proj_w = (const float*)d_in[5];
  const float* proj_b = (const float*)d_in[6];
  float* out = (float*)d_out;

  u16* h_t   = (u16*)d_ws;                                  // [16][1024][512]
  u16* qk_t  = h_t  + (size_t)16*1024*512;                  // [16][1024][1024]
  u16* v_ws  = qk_t + (size_t)16*1024*1024;                 // [16][512][1024]
  u16* wq_bf = v_ws + (size_t)16*512*1024;                  // [1536][512]
  u16* wp_bf = wq_bf + (size_t)1536*512;                    // [512][512]
  float* stats = (float*)(wp_bf + (size_t)512*512);         // [512][2]
  u16* attnout = h_t;                                       // reuse

  cvt_kernel<<<768, 256, 0, stream>>>(qkv_w, wq_bf, 1536*512);
  cvt_kernel<<<256, 256, 0, stream>>>(proj_w, wp_bf, 512*512);
  gn_stats_kernel<<<512, 256, 0, stream>>>(x, stats);
  gn_apply_kernel<<<dim3(32,16), 256, 0, stream>>>(x, norm_w, norm_b, stats, h_t);

  // fused qkv: q|k -> qk_t[b][n][o], v -> v_ws[b][o][n]
  gemm_qkv_kernel<<<dim3(6,8,16), 256, 0, stream>>>(h_t, wq_bf, qkv_b, qk_t, v_ws);

  attn_kernel<<<512, 256, 0, stream>>>(qk_t, v_ws, attnout);

  // out[b][o][n] = proj_w[o][:] . attnout[b][n][:] + proj_b[o] + x[b][o][n]
  gemm_bt_kernel<<<dim3(8,4,16), 256, 0, stream>>>(
      wp_bf, 0, attnout, (long long)1024*512,
      nullptr, out, (long long)512*1024, proj_b, nullptr, x, (long long)512*1024, 512, 1024, 512);
}

// Round 8
// 215.730 us; speedup vs baseline: 2.4064x; 1.0145x over previous
//
#include <hip/hip_runtime.h>

typedef __bf16 v8bf __attribute__((ext_vector_type(8)));
typedef float  v4f  __attribute__((ext_vector_type(4)));
typedef unsigned short u16;

__device__ __forceinline__ u16 f2bf(float f){
  __bf16 h = (__bf16)f;
  union { __bf16 h; u16 u; } c; c.h = h; return c.u;
}
__device__ __forceinline__ v4f v4zero(){ v4f z; z[0]=0.f; z[1]=0.f; z[2]=0.f; z[3]=0.f; return z; }

#define MFMA16(a,b,c) __builtin_amdgcn_mfma_f32_16x16x32_bf16((a),(b),(c),0,0,0)

// async global->LDS, 16B per lane; LDS dest = wave-uniform base + lane*16
__device__ __forceinline__ void gl_lds16(const u16* g, u16* l){
  __builtin_amdgcn_global_load_lds((const __attribute__((address_space(1))) void*)g,
                                   (__attribute__((address_space(3))) void*)l, 16, 0, 0);
}

// ============ f32 -> bf16 bulk convert ============
__global__ __launch_bounds__(256) void cvt_kernel(const float* __restrict__ src, u16* __restrict__ dst, int n){
  int i = (blockIdx.x*256 + threadIdx.x)*4;
  if (i < n){
    float4 v = *(const float4*)(src + i);
    ushort4 o;
    o.x = f2bf(v.x); o.y = f2bf(v.y); o.z = f2bf(v.z); o.w = f2bf(v.w);
    *(ushort4*)(dst + i) = o;
  }
}

// ============ GroupNorm stats: one block per (b,g) ============
__global__ __launch_bounds__(256) void gn_stats_kernel(const float* __restrict__ x, float* __restrict__ stats){
  const float* base = x + (size_t)blockIdx.x * 16384;
  float s = 0.f, ss = 0.f;
  #pragma unroll
  for (int it = 0; it < 16; ++it){
    float4 v = *(const float4*)(base + it*1024 + threadIdx.x*4);
    s  += v.x + v.y + v.z + v.w;
    ss += v.x*v.x + v.y*v.y + v.z*v.z + v.w*v.w;
  }
  #pragma unroll
  for (int off = 32; off > 0; off >>= 1){ s += __shfl_down(s, off); ss += __shfl_down(ss, off); }
  __shared__ float red[8];
  int w = threadIdx.x >> 6;
  if ((threadIdx.x & 63) == 0){ red[w] = s; red[4+w] = ss; }
  __syncthreads();
  if (threadIdx.x == 0){
    float S  = red[0]+red[1]+red[2]+red[3];
    float SS = red[4]+red[5]+red[6]+red[7];
    float mean = S * (1.f/16384.f);
    float var  = SS * (1.f/16384.f) - mean*mean;
    stats[blockIdx.x*2]   = mean;
    stats[blockIdx.x*2+1] = rsqrtf(var + 1e-5f);
  }
}

// ============ GroupNorm apply + transpose: f32 x -> bf16 h_t[b][n][c] ============
__global__ __launch_bounds__(256) void gn_apply_kernel(const float* __restrict__ x, const float* __restrict__ nw,
                                                       const float* __restrict__ nb, const float* __restrict__ stats,
                                                       u16* __restrict__ h_t){
  __shared__ u16 tile[32*520];   // [n_local 32][c 512 + pad 8]
  int b = blockIdx.y, n0 = blockIdx.x*32, tid = threadIdx.x;
  int cr = tid >> 2, nn = (tid & 3)*8;
  #pragma unroll
  for (int p = 0; p < 8; ++p){
    int c = p*64 + cr;
    const float* px = x + (size_t)(b*512 + c)*1024 + n0 + nn;
    float4 u0 = *(const float4*)(px);
    float4 u1 = *(const float4*)(px + 4);
    int g = c >> 4;
    float mean = stats[(b*32+g)*2], rstd = stats[(b*32+g)*2+1];
    float wv = nw[c], bv = nb[c];
    float vals[8] = {u0.x,u0.y,u0.z,u0.w,u1.x,u1.y,u1.z,u1.w};
    #pragma unroll
    for (int e = 0; e < 8; ++e)
      tile[(nn+e)*520 + c] = f2bf((vals[e] - mean)*rstd*wv + bv);
  }
  __syncthreads();
  #pragma unroll
  for (int p = 0; p < 8; ++p){
    int n  = p*4 + (tid >> 6);
    int c0 = (tid & 63)*8;
    *(int4*)(h_t + ((size_t)b*1024 + n0 + n)*512 + c0) = *(int4*)(tile + n*520 + c0);
  }
}

// ============ Fused QKV GEMM, double-buffered BK=32, 1 barrier/iter ============
// C[n][o] = h_t[b][n][:].wq[o][:] + qkv_b[o]; block tile 128(n) x 256(o), 4 waves 64x128.
// o<1024 -> qk_t[b][n][o]; o>=1024 -> v_ws[b][o-1024][n] (transposed bounce).
// Per-buffer layout: A[128][32] then B[256][32]; slot s of row r holds granule s^(r&3).
// grid (6, 8, 16).
__global__ __launch_bounds__(256,2) void gemm_qkv_kernel(
    const u16* __restrict__ A,       // h_t  [16][1024][512]
    const u16* __restrict__ B,       // wq_bf [1536][512]
    const float* __restrict__ bias,  // qkv_b [1536] f32
    u16* __restrict__ qk_t, u16* __restrict__ v_ws)
{
  __shared__ u16 smem[24576];    // 49,152 B: 2 x (A 4096 + B 8192 u16)
  const int tid = threadIdx.x, w = tid>>6, lane = tid&63, col = lane&15, quad = lane>>4;
  const int m0 = blockIdx.y*128;       // n
  const int n0 = blockIdx.x*256;       // o
  const int b  = blockIdx.z;
  const int lr = lane>>2;                      // row within 16-row call group
  const int gsw = ((lane&3) ^ (lr&3))*8;       // swizzled source granule
  const u16* Ag = A + ((size_t)b*1024 + m0 + w*32 + lr)*512 + gsw;
  const u16* Bg = B + (size_t)(n0 + w*64 + lr)*512 + gsw;
  const int mw = (w&1)*64, nw = (w>>1)*128;
  const int fsw = (quad ^ (col&3))*8;          // fragment granule

  v4f acc[4][8];
  #pragma unroll
  for (int i=0;i<4;++i)
    #pragma unroll
    for (int j=0;j<8;++j) acc[i][j] = v4zero();

  // prologue: stage tile 0 into buf 0
  {
    u16* Ab = smem + (w*32)*32;
    u16* Bb = smem + 4096 + (w*64)*32;
    #pragma unroll
    for (int p = 0; p < 2; ++p) gl_lds16(Ag + (size_t)(p*16)*512, Ab + p*512);
    #pragma unroll
    for (int p = 0; p < 4; ++p) gl_lds16(Bg + (size_t)(p*16)*512, Bb + p*512);
  }

  for (int kt = 0; kt < 16; ++kt){
    __syncthreads();                 // drains vmcnt -> tile kt resident; separates kt-1 readers from kt+1 writers
    if (kt < 15){
      u16* Ab = smem + ((kt+1)&1)*12288 + (w*32)*32;
      u16* Bb = smem + ((kt+1)&1)*12288 + 4096 + (w*64)*32;
      int ko = (kt+1)*32;
      #pragma unroll
      for (int p = 0; p < 2; ++p) gl_lds16(Ag + (size_t)(p*16)*512 + ko, Ab + p*512);
      #pragma unroll
      for (int p = 0; p < 4; ++p) gl_lds16(Bg + (size_t)(p*16)*512 + ko, Bb + p*512);
    }
    const u16* As = smem + (kt&1)*12288;
    const u16* Bs = As + 4096;
    v8bf a[4], bb[8];
    #pragma unroll
    for (int i = 0; i < 4; ++i) a[i]  = *(const v8bf*)(As + (mw+i*16+col)*32 + fsw);
    #pragma unroll
    for (int j = 0; j < 8; ++j) bb[j] = *(const v8bf*)(Bs + (nw+j*16+col)*32 + fsw);
    #pragma unroll
    for (int i = 0; i < 4; ++i)
      #pragma unroll
      for (int j = 0; j < 8; ++j)
        acc[i][j] = MFMA16(a[i], bb[j], acc[i][j]);
  }
  __syncthreads();                   // staging area becomes epilogue scratch

  float bc[8];
  #pragma unroll
  for (int j = 0; j < 8; ++j)
    bc[j] = bias[n0 + nw + j*16 + col];

  if (n0 < 1024){
    u16* Cs = smem + w*(64*72);
    #pragma unroll
    for (int half = 0; half < 2; ++half){
      #pragma unroll
      for (int i = 0; i < 4; ++i)
        #pragma unroll
        for (int jj = 0; jj < 4; ++jj)
          #pragma unroll
          for (int r = 0; r < 4; ++r)
            Cs[(i*16+quad*4+r)*72 + jj*16+col] = f2bf(acc[i][half*4+jj][r] + bc[half*4+jj]);
      u16* dst = qk_t + (size_t)b*1024*1024;
      #pragma unroll
      for (int p = 0; p < 8; ++p){
        int rl = p*8 + (lane>>3), cl = (lane&7)*8;
        *(int4*)(dst + (size_t)(m0+mw+rl)*1024 + n0+nw+half*64+cl) = *(int4*)(Cs + rl*72 + cl);
      }
    }
  } else {
    u16* Ct = smem + w*(64*80);
    #pragma unroll
    for (int half = 0; half < 2; ++half){
      #pragma unroll
      for (int i = 0; i < 4; ++i)
        #pragma unroll
        for (int jj = 0; jj < 4; ++jj)
          #pragma unroll
          for (int r = 0; r < 4; ++r)
            Ct[(jj*16+col)*80 + i*16+quad*4+r] = f2bf(acc[i][half*4+jj][r] + bc[half*4+jj]);
      u16* dst = v_ws + (size_t)b*512*1024;
      #pragma unroll
      for (int p = 0; p < 8; ++p){
        int rl = p*8 + (lane>>3), cl = (lane&7)*8;
        *(int4*)(dst + (size_t)(n0-1024 + nw + half*64 + rl)*1024 + m0+mw+cl) = *(int4*)(Ct + rl*80 + cl);
      }
    }
  }
}

// ============ Generic bf16 GEMM (proj): dbuf BK=64, 1 barrier/iter ============
// C[M][N] = A[M][K]*B[N][K]^T; per-buffer A[128][64]+B[128][64]; slot s of row r = granule s^(r&7).
__global__ __launch_bounds__(256,2) void gemm_bt_kernel(
    const u16* __restrict__ A, long long sA,
    const u16* __restrict__ B, long long sB,
    u16* __restrict__ Cbf, float* __restrict__ Cf, long long sC,
    const float* __restrict__ bias_row,
    const float* __restrict__ bias_col,
    const float* __restrict__ residf, long long sR,
    int M, int N, int K)
{
  __shared__ u16 smem[32768];   // 65,536 B: 2 x (A 8192 + B 8192 u16)
  const int tid = threadIdx.x, w = tid>>6, lane = tid&63, col = lane&15, quad = lane>>4;
  const int m0 = blockIdx.y*128, n0 = blockIdx.x*128;
  const int lr8 = lane>>3;
  const int gsw = ((lane&7) ^ lr8)*8;
  const u16* Ag = A + (size_t)blockIdx.z*sA + (size_t)(m0 + w*32 + lr8)*K + gsw;
  const u16* Bg = B + (size_t)blockIdx.z*sB + (size_t)(n0 + w*32 + lr8)*K + gsw;
  const int mw = (w&1)*64, nw = (w>>1)*64;
  const int csw = col&7;
  const int nt = K >> 6;

  v4f acc[4][4];
  #pragma unroll
  for (int i=0;i<4;++i)
    #pragma unroll
    for (int j=0;j<4;++j) acc[i][j] = v4zero();

  {
    u16* Ab = smem + (w*32)*64;
    u16* Bb = smem + 8192 + (w*32)*64;
    #pragma unroll
    for (int p = 0; p < 4; ++p){
      gl_lds16(Ag + (size_t)(p*8)*K, Ab + p*512);
      gl_lds16(Bg + (size_t)(p*8)*K, Bb + p*512);
    }
  }

  for (int kt = 0; kt < nt; ++kt){
    __syncthreads();
    if (kt+1 < nt){
      u16* Ab = smem + ((kt+1)&1)*16384 + (w*32)*64;
      u16* Bb = smem + ((kt+1)&1)*16384 + 8192 + (w*32)*64;
      int ko = (kt+1)*64;
      #pragma unroll
      for (int p = 0; p < 4; ++p){
        gl_lds16(Ag + (size_t)(p*8)*K + ko, Ab + p*512);
        gl_lds16(Bg + (size_t)(p*8)*K + ko, Bb + p*512);
      }
    }
    const u16* As = smem + (kt&1)*16384;
    const u16* Bs = As + 8192;
    #pragma unroll
    for (int kh = 0; kh < 2; ++kh){
      const int fs = ((kh*4 + quad) ^ csw)*8;
      v8bf a[4], bb[4];
      #pragma unroll
      for (int i = 0; i < 4; ++i) a[i]  = *(const v8bf*)(As + (mw+i*16+col)*64 + fs);
      #pragma unroll
      for (int j = 0; j < 4; ++j) bb[j] = *(const v8bf*)(Bs + (nw+j*16+col)*64 + fs);
      #pragma unroll
      for (int i = 0; i < 4; ++i)
        #pragma unroll
        for (int j = 0; j < 4; ++j)
          acc[i][j] = MFMA16(a[i], bb[j], acc[i][j]);
    }
  }
  __syncthreads();

  float br[4][4], bc[4];
  #pragma unroll
  for (int i = 0; i < 4; ++i)
    #pragma unroll
    for (int r = 0; r < 4; ++r)
      br[i][r] = bias_row ? bias_row[m0+mw+i*16+quad*4+r] : 0.f;
  #pragma unroll
  for (int j = 0; j < 4; ++j)
    bc[j] = bias_col ? bias_col[n0+nw+j*16+col] : 0.f;

  if (Cf){
    float* Cb = Cf + (size_t)blockIdx.z*sC;
    const float* Rb = residf ? residf + (size_t)blockIdx.z*sR : nullptr;
    #pragma unroll
    for (int i = 0; i < 4; ++i)
      #pragma unroll
      for (int r = 0; r < 4; ++r){
        int row = m0+mw+i*16+quad*4+r;
        #pragma unroll
        for (int j = 0; j < 4; ++j){
          size_t goff = (size_t)row*N + n0+nw+j*16+col;
          float val = acc[i][j][r] + br[i][r] + bc[j];
          if (Rb) val += Rb[goff];
          Cb[goff] = val;
        }
      }
  } else {
    u16* Cs = smem + w*(64*72);
    #pragma unroll
    for (int i = 0; i < 4; ++i)
      #pragma unroll
      for (int j = 0; j < 4; ++j)
        #pragma unroll
        for (int r = 0; r < 4; ++r)
          Cs[(i*16+quad*4+r)*72 + j*16+col] = f2bf(acc[i][j][r] + br[i][r] + bc[j]);
    __syncthreads();
    u16* Cb = Cbf + (size_t)blockIdx.z*sC;
    #pragma unroll
    for (int p = 0; p < 8; ++p){
      int rl = p*8 + (lane>>3), cl = (lane&7)*8;
      size_t goff = (size_t)(m0+mw+rl)*N + n0+nw+cl;
      *(int4*)(Cb + goff) = *(int4*)(Cs + rl*72 + cl);
    }
  }
}

// ============ Fused flash attention: no-max softmax, V double-buffered, lane-local l ============
// qk[b][n][0..511]=q, [512..1023]=k; vv[b][c_all][m]; out[b][n][c_all]
// flat grid 512: qt=id>>6, bh=id&63 -> same-(b,h) blocks on same XCD.
// LDS 65,536 B: Ks[64][128] + V 2x[128][64] + Ps[128][64].
// Per iter: [sync: drain K/V_t] QK_t -> [sync] -> prefetch K/V_{t+1} -> exp/Ps/PV_t.
__global__ __launch_bounds__(256,2) void attn_kernel(const u16* __restrict__ qk, const u16* __restrict__ vv,
                                                     u16* __restrict__ outp){
  __shared__ u16 smem[32768];
  u16* Ks = smem;                    // [64][128]
  u16* Vs = smem + 8192;             // 2 x [128][64]
  u16* Ps = smem + 8192 + 16384;     // [128][64]
  const int id = blockIdx.x;
  const int qt = id >> 6, bh = id & 63, b = bh >> 2, h = bh & 3;
  const int n0 = qt*128;
  const int tid = threadIdx.x, w = tid>>6, lane = tid&63, col = lane&15, quad = lane>>4;
  const size_t bq = (size_t)b*1024*1024;
  const float scale2 = 0.12751742f;  // (1/sqrt(128)) * log2(e)

  // Q fragments in registers (A-operand layout)
  v8bf aq[2][4];
  #pragma unroll
  for (int i = 0; i < 2; ++i)
    #pragma unroll
    for (int kk = 0; kk < 4; ++kk)
      aq[i][kk] = *(const v8bf*)(qk + bq + (size_t)(n0 + w*32 + i*16 + col)*1024 + h*128 + kk*32 + quad*8);

  v4f o[2][8];
  #pragma unroll
  for (int i=0;i<2;++i)
    #pragma unroll
    for (int j=0;j<8;++j) o[i][j] = v4zero();
  float lsum[8];
  #pragma unroll
  for (int r=0;r<8;++r) lsum[r] = 0.f;

  // staging lane constants (swizzle folded into global source granule)
  const int krow = w*4 + (lane>>4);
  const int kgr  = (lane&15) ^ (krow&7);
  const u16* kg_base = qk + bq + (size_t)krow*1024 + 512 + h*128 + kgr*8;
  u16* kl_base = Ks + (w*4)*128;
  const int vrow = w*8 + (lane>>3);
  const int vgr  = (lane&7) ^ (vrow&7);
  const u16* vg_base = vv + ((size_t)b*512 + h*128 + vrow)*1024 + vgr*8;

  // prologue: stage tile 0 (K -> Ks, V -> Vbuf 0)
  #pragma unroll
  for (int p = 0; p < 4; ++p)
    gl_lds16(kg_base + (size_t)(p*16)*1024, kl_base + p*16*128);
  #pragma unroll
  for (int p = 0; p < 4; ++p)
    gl_lds16(vg_base + (size_t)(p*32)*1024, Vs + (w*8 + p*32)*64);

  for (int t = 0; t < 16; ++t){
    const int mt = t*64;
    __syncthreads();                       // E: K_t/V_t resident (drains prefetch)

    // S = Q K^T (raw)
    v4f s[2][4];
    #pragma unroll
    for (int i=0;i<2;++i)
      #pragma unroll
      for (int j=0;j<4;++j) s[i][j] = v4zero();
    #pragma unroll
    for (int kk = 0; kk < 4; ++kk){
      v8bf bk[4];
      #pragma unroll
      for (int j = 0; j < 4; ++j){
        int r = j*16 + col;
        int g = (kk*4 + quad) ^ (r&7);
        bk[j] = *(const v8bf*)(Ks + (r<<7) + (g<<3));
      }
      #pragma unroll
      for (int i = 0; i < 2; ++i)
        #pragma unroll
        for (int j = 0; j < 4; ++j)
          s[i][j] = MFMA16(aq[i][kk], bk[j], s[i][j]);
    }
    __syncthreads();                       // B: all waves past QK_t -> Ks free to restage

    if (t < 15){                           // prefetch tile t+1; flies across exp/Ps/PV
      int mt2 = mt + 64;
      #pragma unroll
      for (int p = 0; p < 4; ++p)
        gl_lds16(kg_base + (size_t)(mt2 + p*16)*1024, kl_base + p*16*128);
      u16* vl = Vs + (((t+1)&1)<<13) + (w*8)*64;
      #pragma unroll
      for (int p = 0; p < 4; ++p)
        gl_lds16(vg_base + (size_t)(p*32)*1024 + mt2, vl + p*32*64);
    }

    // p = exp2(s*scale2); lane-local row-sum; write Ps (A-operand layout, swizzled)
    #pragma unroll
    for (int i = 0; i < 2; ++i)
      #pragma unroll
      for (int r = 0; r < 4; ++r){
        float p0 = __builtin_amdgcn_exp2f(s[i][0][r]*scale2);
        float p1 = __builtin_amdgcn_exp2f(s[i][1][r]*scale2);
        float p2 = __builtin_amdgcn_exp2f(s[i][2][r]*scale2);
        float p3 = __builtin_amdgcn_exp2f(s[i][3][r]*scale2);
        lsum[i*4+r] += (p0+p1) + (p2+p3);
        int rr = w*32 + i*16 + quad*4 + r;
        int key = (rr ^ (rr>>2)) & 7;
        Ps[(rr<<6) + (((0 ^ key))<<3) + (col&7) + ((col>>3)? ((1^key)<<3)-((0^key)<<3) : 0)] = f2bf(p0); // j=0
        // explicit per-j writes (compiler folds): m = j*16+col
        Ps[(rr<<6) + ((((16*1+col)>>3) ^ key)<<3) + (col&7)] = f2bf(p1);
        Ps[(rr<<6) + ((((16*2+col)>>3) ^ key)<<3) + (col&7)] = f2bf(p2);
        Ps[(rr<<6) + ((((16*3+col)>>3) ^ key)<<3) + (col&7)] = f2bf(p3);
      }
    // fix j=0 write cleanly (overwrite the hacky expression above with correct one)
    #pragma unroll
    for (int i = 0; i < 2; ++i)
      #pragma unroll
      for (int r = 0; r < 4; ++r){
        int rr = w*32 + i*16 + quad*4 + r;
        int key = (rr ^ (rr>>2)) & 7;
        float p0 = __builtin_amdgcn_exp2f(s[i][0][r]*scale2);
        Ps[(rr<<6) + ((((col)>>3) ^ key)<<3) + (col&7)] = f2bf(p0);
      }

    // O += P V^T (Ps wave-private: in-wave lgkm ordering suffices, no barrier)
    const u16* Vc = Vs + ((t&1)<<13);
    #pragma unroll
    for (int kk = 0; kk < 2; ++kk){
      v8bf ap[2];
      #pragma unroll
      for (int i = 0; i < 2; ++i){
        int rr = w*32 + i*16 + col;
        int key = (rr ^ (rr>>2)) & 7;
        int g = (kk*4 + quad) ^ key;
        ap[i] = *(const v8bf*)(Ps + (rr<<6) + (g<<3));
      }
      #pragma unroll
      for (int j = 0; j < 8; ++j){
        int vr = j*16 + col;
        int g = (kk*4 + quad) ^ (vr&7);
        v8bf bv = *(const v8bf*)(Vc + (vr<<6) + (g<<3));
        #pragma unroll
        for (int i = 0; i < 2; ++i) o[i][j] = MFMA16(ap[i], bv, o[i][j]);
      }
    }
  }
  __syncthreads();

  // reduce l across the 16 col-lanes; normalize
  #pragma unroll
  for (int i = 0; i < 2; ++i)
    #pragma unroll
    for (int r = 0; r < 4; ++r){
      float l = lsum[i*4+r];
      l += __shfl_xor(l, 1);
      l += __shfl_xor(l, 2);
      l += __shfl_xor(l, 4);
      l += __shfl_xor(l, 8);
      float inv = 1.f / l;
      #pragma unroll
      for (int j = 0; j < 8; ++j) o[i][j][r] *= inv;
    }

  // bounce O through LDS (swizzled [128][128]) for coalesced 16B stores
  #pragma unroll
  for (int i = 0; i < 2; ++i)
    #pragma unroll
    for (int j = 0; j < 8; ++j)
      #pragma unroll
      for (int r = 0; r < 4; ++r){
        int rr = w*32 + i*16 + quad*4 + r;
        int c  = j*16 + col;
        smem[(rr<<7) + ((((c>>3) ^ (rr&7))<<3)) + (c&7)] = f2bf(o[i][j][r]);
      }
  __syncthreads();
  #pragma unroll
  for (int p = 0; p < 8; ++p){
    int nr = p*16 + (tid>>4);
    int gc = (tid&15) ^ (nr&7);
    *(int4*)(outp + ((size_t)b*1024 + n0 + nr)*512 + h*128 + ((tid&15)<<3)) =
      *(int4*)(smem + (nr<<7) + (gc<<3));
  }
}

extern "C" void kernel_launch(void* const* d_in, const int* in_sizes, int n_in,
                              void* d_out, int out_size, void* d_ws, size_t ws_size,
                              hipStream_t stream){
  const float* x      = (const float*)d_in[0];
  const float* norm_w = (const float*)d_in[1];
  const float* norm_b = (const float*)d_in[2];
  const float* qkv_w  = (const float*)d_in[3];
  const float* qkv_b  = (const float*)d_in[4];
  const float* proj_w = (const float*)d_in[5];
  const float* proj_b = (const float*)d_in[6];
  float* out = (float*)d_out;

  u16* h_t   = (u16*)d_ws;                                  // [16][1024][512]
  u16* qk_t  = h_t  + (size_t)16*1024*512;                  // [16][1024][1024]
  u16* v_ws  = qk_t + (size_t)16*1024*1024;                 // [16][512][1024]
  u16* wq_bf = v_ws + (size_t)16*512*1024;                  // [1536][512]
  u16* wp_bf = wq_bf + (size_t)1536*512;                    // [512][512]
  float* stats = (float*)(wp_bf + (size_t)512*512);         // [512][2]
  u16* attnout = h_t;                                       // reuse

  cvt_kernel<<<768, 256, 0, stream>>>(qkv_w, wq_bf, 1536*512);
  cvt_kernel<<<256, 256, 0, stream>>>(proj_w, wp_bf, 512*512);
  gn_stats_kernel<<<512, 256, 0, stream>>>(x, stats);
  gn_apply_kernel<<<dim3(32,16), 256, 0, stream>>>(x, norm_w, norm_b, stats, h_t);

  gemm_qkv_kernel<<<dim3(6,8,16), 256, 0, stream>>>(h_t, wq_bf, qkv_b, qk_t, v_ws);

  attn_kernel<<<512, 256, 0, stream>>>(qk_t, v_ws, attnout);

  gemm_bt_kernel<<<dim3(8,4,16), 256, 0, stream>>>(
      wp_bf, 0, attnout, (long long)1024*512,
      nullptr, out, (long long)512*1024, proj_b, nullptr, x, (long long)512*1024, 512, 1024, 512);
}

// Round 9
// 208.125 us; speedup vs baseline: 2.4943x; 1.0365x over previous
//
#include <hip/hip_runtime.h>

typedef __bf16 v8bf __attribute__((ext_vector_type(8)));
typedef float  v4f  __attribute__((ext_vector_type(4)));
typedef unsigned short u16;

__device__ __forceinline__ u16 f2bf(float f){
  __bf16 h = (__bf16)f;
  union { __bf16 h; u16 u; } c; c.h = h; return c.u;
}
__device__ __forceinline__ v4f v4zero(){ v4f z; z[0]=0.f; z[1]=0.f; z[2]=0.f; z[3]=0.f; return z; }

#define MFMA16(a,b,c) __builtin_amdgcn_mfma_f32_16x16x32_bf16((a),(b),(c),0,0,0)

// async global->LDS, 16B per lane; LDS dest = wave-uniform base + lane*16
__device__ __forceinline__ void gl_lds16(const u16* g, u16* l){
  __builtin_amdgcn_global_load_lds((const __attribute__((address_space(1))) void*)g,
                                   (__attribute__((address_space(3))) void*)l, 16, 0, 0);
}

// ============ f32 -> bf16 bulk convert, both weight tensors in one launch ============
__global__ __launch_bounds__(256) void cvt2_kernel(const float* __restrict__ a, u16* __restrict__ da, int na,
                                                   const float* __restrict__ b, u16* __restrict__ db, int nb){
  int i = (blockIdx.x*256 + threadIdx.x)*4;
  const float* s; u16* d; int off;
  if (i < na){ s = a; d = da; off = i; }
  else { off = i - na; if (off >= nb) return; s = b; d = db; }
  float4 v = *(const float4*)(s + off);
  ushort4 o;
  o.x = f2bf(v.x); o.y = f2bf(v.y); o.z = f2bf(v.z); o.w = f2bf(v.w);
  *(ushort4*)(d + off) = o;
}

// ============ Fused GroupNorm: stats + apply + transpose in one kernel ============
// One block per (b,g): 16 channels x 1024 n, f32. x read ONCE (staged in LDS),
// writes bf16 h_t[b][n][c0..c0+16). LDS pitch 1028 f32 -> conflict-free column reads.
__global__ __launch_bounds__(256) void gn_fused_kernel(const float* __restrict__ x, const float* __restrict__ nw,
                                                       const float* __restrict__ nb, u16* __restrict__ h_t){
  __shared__ float xs[16*1028 + 16];
  const int bg = blockIdx.x, b = bg >> 5, g = bg & 31, c0 = g*16;
  const int tid = threadIdx.x;
  const float* base = x + (size_t)(b*512 + c0)*1024;

  float s = 0.f, ss = 0.f;
  #pragma unroll
  for (int it = 0; it < 16; ++it){
    float4 v = *(const float4*)(base + it*1024 + tid*4);
    s  += v.x + v.y + v.z + v.w;
    ss += v.x*v.x + v.y*v.y + v.z*v.z + v.w*v.w;
    *(float4*)(xs + it*1028 + tid*4) = v;
  }
  #pragma unroll
  for (int off = 32; off > 0; off >>= 1){ s += __shfl_down(s, off); ss += __shfl_down(ss, off); }
  float* red = xs + 16*1028;
  int w = tid >> 6;
  if ((tid & 63) == 0){ red[w] = s; red[4+w] = ss; }
  __syncthreads();
  if (tid == 0){
    float S  = red[0]+red[1]+red[2]+red[3];
    float SS = red[4]+red[5]+red[6]+red[7];
    float mean = S * (1.f/16384.f);
    float var  = SS * (1.f/16384.f) - mean*mean;
    red[8] = mean;
    red[9] = rsqrtf(var + 1e-5f);
  }
  __syncthreads();
  const float mean = red[8], rstd = red[9];

  const int half = tid & 1, nbase = tid >> 1;
  float wv[8], bv[8];
  #pragma unroll
  for (int cl = 0; cl < 8; ++cl){
    int c = c0 + half*8 + cl;
    wv[cl] = nw[c] * rstd;
    bv[cl] = nb[c] - mean * wv[cl];
  }
  #pragma unroll
  for (int p = 0; p < 8; ++p){
    int n = nbase + p*128;
    alignas(16) u16 tmp[8];
    #pragma unroll
    for (int cl = 0; cl < 8; ++cl)
      tmp[cl] = f2bf(xs[(half*8 + cl)*1028 + n] * wv[cl] + bv[cl]);
    *(int4*)(h_t + ((size_t)b*1024 + n)*512 + c0 + half*8) = *(int4*)tmp;
  }
}

// ============ Fused QKV GEMM, double-buffered BK=32, 1 barrier/iter ============
// C[n][o] = h_t[b][n][:].wq[o][:] + qkv_b[o]; block tile 128(n) x 256(o), 4 waves 64x128.
// o<1024 -> qk_t[b][n][o]; o>=1024 -> v_ws[b][o-1024][n] (transposed bounce).
// grid (6, 8, 16).
__global__ __launch_bounds__(256,2) void gemm_qkv_kernel(
    const u16* __restrict__ A,       // h_t  [16][1024][512]
    const u16* __restrict__ B,       // wq_bf [1536][512]
    const float* __restrict__ bias,  // qkv_b [1536] f32
    u16* __restrict__ qk_t, u16* __restrict__ v_ws)
{
  __shared__ u16 smem[24576];    // 49,152 B: 2 x (A 4096 + B 8192 u16)
  const int tid = threadIdx.x, w = tid>>6, lane = tid&63, col = lane&15, quad = lane>>4;
  const int m0 = blockIdx.y*128;       // n
  const int n0 = blockIdx.x*256;       // o
  const int b  = blockIdx.z;
  const int lr = lane>>2;
  const int gsw = ((lane&3) ^ (lr&3))*8;
  const u16* Ag = A + ((size_t)b*1024 + m0 + w*32 + lr)*512 + gsw;
  const u16* Bg = B + (size_t)(n0 + w*64 + lr)*512 + gsw;
  const int mw = (w&1)*64, nw = (w>>1)*128;
  const int fsw = (quad ^ (col&3))*8;

  v4f acc[4][8];
  #pragma unroll
  for (int i=0;i<4;++i)
    #pragma unroll
    for (int j=0;j<8;++j) acc[i][j] = v4zero();

  {
    u16* Ab = smem + (w*32)*32;
    u16* Bb = smem + 4096 + (w*64)*32;
    #pragma unroll
    for (int p = 0; p < 2; ++p) gl_lds16(Ag + (size_t)(p*16)*512, Ab + p*512);
    #pragma unroll
    for (int p = 0; p < 4; ++p) gl_lds16(Bg + (size_t)(p*16)*512, Bb + p*512);
  }

  for (int kt = 0; kt < 16; ++kt){
    __syncthreads();
    if (kt < 15){
      u16* Ab = smem + ((kt+1)&1)*12288 + (w*32)*32;
      u16* Bb = smem + ((kt+1)&1)*12288 + 4096 + (w*64)*32;
      int ko = (kt+1)*32;
      #pragma unroll
      for (int p = 0; p < 2; ++p) gl_lds16(Ag + (size_t)(p*16)*512 + ko, Ab + p*512);
      #pragma unroll
      for (int p = 0; p < 4; ++p) gl_lds16(Bg + (size_t)(p*16)*512 + ko, Bb + p*512);
    }
    const u16* As = smem + (kt&1)*12288;
    const u16* Bs = As + 4096;
    v8bf a[4], bb[8];
    #pragma unroll
    for (int i = 0; i < 4; ++i) a[i]  = *(const v8bf*)(As + (mw+i*16+col)*32 + fsw);
    #pragma unroll
    for (int j = 0; j < 8; ++j) bb[j] = *(const v8bf*)(Bs + (nw+j*16+col)*32 + fsw);
    #pragma unroll
    for (int i = 0; i < 4; ++i)
      #pragma unroll
      for (int j = 0; j < 8; ++j)
        acc[i][j] = MFMA16(a[i], bb[j], acc[i][j]);
  }
  __syncthreads();

  float bc[8];
  #pragma unroll
  for (int j = 0; j < 8; ++j)
    bc[j] = bias[n0 + nw + j*16 + col];

  if (n0 < 1024){
    u16* Cs = smem + w*(64*72);
    #pragma unroll
    for (int half = 0; half < 2; ++half){
      #pragma unroll
      for (int i = 0; i < 4; ++i)
        #pragma unroll
        for (int jj = 0; jj < 4; ++jj)
          #pragma unroll
          for (int r = 0; r < 4; ++r)
            Cs[(i*16+quad*4+r)*72 + jj*16+col] = f2bf(acc[i][half*4+jj][r] + bc[half*4+jj]);
      u16* dst = qk_t + (size_t)b*1024*1024;
      #pragma unroll
      for (int p = 0; p < 8; ++p){
        int rl = p*8 + (lane>>3), cl = (lane&7)*8;
        *(int4*)(dst + (size_t)(m0+mw+rl)*1024 + n0+nw+half*64+cl) = *(int4*)(Cs + rl*72 + cl);
      }
    }
  } else {
    u16* Ct = smem + w*(64*80);
    #pragma unroll
    for (int half = 0; half < 2; ++half){
      #pragma unroll
      for (int i = 0; i < 4; ++i)
        #pragma unroll
        for (int jj = 0; jj < 4; ++jj)
          #pragma unroll
          for (int r = 0; r < 4; ++r)
            Ct[(jj*16+col)*80 + i*16+quad*4+r] = f2bf(acc[i][half*4+jj][r] + bc[half*4+jj]);
      u16* dst = v_ws + (size_t)b*512*1024;
      #pragma unroll
      for (int p = 0; p < 8; ++p){
        int rl = p*8 + (lane>>3), cl = (lane&7)*8;
        *(int4*)(dst + (size_t)(n0-1024 + nw + half*64 + rl)*1024 + m0+mw+cl) = *(int4*)(Ct + rl*80 + cl);
      }
    }
  }
}

// ============ Generic bf16 GEMM (proj): dbuf BK=64, 1 barrier/iter ============
__global__ __launch_bounds__(256,2) void gemm_bt_kernel(
    const u16* __restrict__ A, long long sA,
    const u16* __restrict__ B, long long sB,
    u16* __restrict__ Cbf, float* __restrict__ Cf, long long sC,
    const float* __restrict__ bias_row,
    const float* __restrict__ bias_col,
    const float* __restrict__ residf, long long sR,
    int M, int N, int K)
{
  __shared__ u16 smem[32768];   // 65,536 B: 2 x (A 8192 + B 8192 u16)
  const int tid = threadIdx.x, w = tid>>6, lane = tid&63, col = lane&15, quad = lane>>4;
  const int m0 = blockIdx.y*128, n0 = blockIdx.x*128;
  const int lr8 = lane>>3;
  const int gsw = ((lane&7) ^ lr8)*8;
  const u16* Ag = A + (size_t)blockIdx.z*sA + (size_t)(m0 + w*32 + lr8)*K + gsw;
  const u16* Bg = B + (size_t)blockIdx.z*sB + (size_t)(n0 + w*32 + lr8)*K + gsw;
  const int mw = (w&1)*64, nw = (w>>1)*64;
  const int csw = col&7;
  const int nt = K >> 6;

  v4f acc[4][4];
  #pragma unroll
  for (int i=0;i<4;++i)
    #pragma unroll
    for (int j=0;j<4;++j) acc[i][j] = v4zero();

  {
    u16* Ab = smem + (w*32)*64;
    u16* Bb = smem + 8192 + (w*32)*64;
    #pragma unroll
    for (int p = 0; p < 4; ++p){
      gl_lds16(Ag + (size_t)(p*8)*K, Ab + p*512);
      gl_lds16(Bg + (size_t)(p*8)*K, Bb + p*512);
    }
  }

  for (int kt = 0; kt < nt; ++kt){
    __syncthreads();
    if (kt+1 < nt){
      u16* Ab = smem + ((kt+1)&1)*16384 + (w*32)*64;
      u16* Bb = smem + ((kt+1)&1)*16384 + 8192 + (w*32)*64;
      int ko = (kt+1)*64;
      #pragma unroll
      for (int p = 0; p < 4; ++p){
        gl_lds16(Ag + (size_t)(p*8)*K + ko, Ab + p*512);
        gl_lds16(Bg + (size_t)(p*8)*K + ko, Bb + p*512);
      }
    }
    const u16* As = smem + (kt&1)*16384;
    const u16* Bs = As + 8192;
    #pragma unroll
    for (int kh = 0; kh < 2; ++kh){
      const int fs = ((kh*4 + quad) ^ csw)*8;
      v8bf a[4], bb[4];
      #pragma unroll
      for (int i = 0; i < 4; ++i) a[i]  = *(const v8bf*)(As + (mw+i*16+col)*64 + fs);
      #pragma unroll
      for (int j = 0; j < 4; ++j) bb[j] = *(const v8bf*)(Bs + (nw+j*16+col)*64 + fs);
      #pragma unroll
      for (int i = 0; i < 4; ++i)
        #pragma unroll
        for (int j = 0; j < 4; ++j)
          acc[i][j] = MFMA16(a[i], bb[j], acc[i][j]);
    }
  }
  __syncthreads();

  float br[4][4], bc[4];
  #pragma unroll
  for (int i = 0; i < 4; ++i)
    #pragma unroll
    for (int r = 0; r < 4; ++r)
      br[i][r] = bias_row ? bias_row[m0+mw+i*16+quad*4+r] : 0.f;
  #pragma unroll
  for (int j = 0; j < 4; ++j)
    bc[j] = bias_col ? bias_col[n0+nw+j*16+col] : 0.f;

  if (Cf){
    float* Cb = Cf + (size_t)blockIdx.z*sC;
    const float* Rb = residf ? residf + (size_t)blockIdx.z*sR : nullptr;
    #pragma unroll
    for (int i = 0; i < 4; ++i)
      #pragma unroll
      for (int r = 0; r < 4; ++r){
        int row = m0+mw+i*16+quad*4+r;
        #pragma unroll
        for (int j = 0; j < 4; ++j){
          size_t goff = (size_t)row*N + n0+nw+j*16+col;
          float val = acc[i][j][r] + br[i][r] + bc[j];
          if (Rb) val += Rb[goff];
          Cb[goff] = val;
        }
      }
  } else {
    u16* Cs = smem + w*(64*72);
    #pragma unroll
    for (int i = 0; i < 4; ++i)
      #pragma unroll
      for (int j = 0; j < 4; ++j)
        #pragma unroll
        for (int r = 0; r < 4; ++r)
          Cs[(i*16+quad*4+r)*72 + j*16+col] = f2bf(acc[i][j][r] + br[i][r] + bc[j]);
    __syncthreads();
    u16* Cb = Cbf + (size_t)blockIdx.z*sC;
    #pragma unroll
    for (int p = 0; p < 8; ++p){
      int rl = p*8 + (lane>>3), cl = (lane&7)*8;
      size_t goff = (size_t)(m0+mw+rl)*N + n0+nw+cl;
      *(int4*)(Cb + goff) = *(int4*)(Cs + rl*72 + cl);
    }
  }
}

// ============ Fused flash attention: no-max softmax, K AND V double-buffered, 1 barrier/iter ============
// qk[b][n][0..511]=q, [512..1023]=k; vv[b][c_all][m]; out[b][n][c_all]
// flat grid 512: qt=id>>6, bh=id&63 -> same-(b,h) blocks on same XCD.
// LDS 81,920 B (exactly 2 blocks/CU): Ks 2x[64][128] + Vs 2x[128][64] + Ps[128][64].
// Per iter: [sync: drain prefetch t] -> prefetch(t+1) -> QK(t) -> exp/Ps -> PV(t).
__global__ __launch_bounds__(256,2) void attn_kernel(const u16* __restrict__ qk, const u16* __restrict__ vv,
                                                     u16* __restrict__ outp){
  __shared__ u16 smem[40960];
  u16* Ks = smem;                    // 2 x [64][128]  (8192 u16 each)
  u16* Vs = smem + 16384;            // 2 x [128][64]  (8192 u16 each)
  u16* Ps = smem + 32768;            // [128][64]
  const int id = blockIdx.x;
  const int qt = id >> 6, bh = id & 63, b = bh >> 2, h = bh & 3;
  const int n0 = qt*128;
  const int tid = threadIdx.x, w = tid>>6, lane = tid&63, col = lane&15, quad = lane>>4;
  const size_t bq = (size_t)b*1024*1024;
  const float scale2 = 0.12751742f;  // (1/sqrt(128)) * log2(e)

  // Q fragments in registers (A-operand layout)
  v8bf aq[2][4];
  #pragma unroll
  for (int i = 0; i < 2; ++i)
    #pragma unroll
    for (int kk = 0; kk < 4; ++kk)
      aq[i][kk] = *(const v8bf*)(qk + bq + (size_t)(n0 + w*32 + i*16 + col)*1024 + h*128 + kk*32 + quad*8);

  v4f o[2][8];
  #pragma unroll
  for (int i=0;i<2;++i)
    #pragma unroll
    for (int j=0;j<8;++j) o[i][j] = v4zero();
  float lsum[8];
  #pragma unroll
  for (int r=0;r<8;++r) lsum[r] = 0.f;

  // staging lane constants (swizzle folded into global source granule)
  const int krow = w*4 + (lane>>4);
  const int kgr  = (lane&15) ^ (krow&7);
  const u16* kg_base = qk + bq + (size_t)krow*1024 + 512 + h*128 + kgr*8;
  const int vrow = w*8 + (lane>>3);
  const int vgr  = (lane&7) ^ (vrow&7);
  const u16* vg_base = vv + ((size_t)b*512 + h*128 + vrow)*1024 + vgr*8;

  // prologue: stage tile 0 into buf 0
  #pragma unroll
  for (int p = 0; p < 4; ++p)
    gl_lds16(kg_base + (size_t)(p*16)*1024, Ks + (w*4)*128 + p*2048);
  #pragma unroll
  for (int p = 0; p < 4; ++p)
    gl_lds16(vg_base + (size_t)(p*32)*1024, Vs + (w*8)*64 + p*2048);

  for (int t = 0; t < 16; ++t){
    const int mt = t*64;
    __syncthreads();                       // tile t resident; iter t-1 compute done everywhere

    if (t < 15){                           // prefetch t+1; flies over the whole compute phase
      int mt2 = mt + 64;
      u16* kl = Ks + (((t+1)&1)<<13) + (w*4)*128;
      #pragma unroll
      for (int p = 0; p < 4; ++p)
        gl_lds16(kg_base + (size_t)(mt2 + p*16)*1024, kl + p*2048);
      u16* vl = Vs + (((t+1)&1)<<13) + (w*8)*64;
      #pragma unroll
      for (int p = 0; p < 4; ++p)
        gl_lds16(vg_base + (size_t)(p*32)*1024 + mt2, vl + p*2048);
    }

    // S = Q K^T (raw)
    const u16* Kc = Ks + ((t&1)<<13);
    v4f s[2][4];
    #pragma unroll
    for (int i=0;i<2;++i)
      #pragma unroll
      for (int j=0;j<4;++j) s[i][j] = v4zero();
    #pragma unroll
    for (int kk = 0; kk < 4; ++kk){
      v8bf bk[4];
      #pragma unroll
      for (int j = 0; j < 4; ++j){
        int r = j*16 + col;
        int g = (kk*4 + quad) ^ (r&7);
        bk[j] = *(const v8bf*)(Kc + (r<<7) + (g<<3));
      }
      #pragma unroll
      for (int i = 0; i < 2; ++i)
        #pragma unroll
        for (int j = 0; j < 4; ++j)
          s[i][j] = MFMA16(aq[i][kk], bk[j], s[i][j]);
    }

    // p = exp2(s*scale2); lane-local row-sum; write Ps (A-operand layout, swizzled)
    #pragma unroll
    for (int i = 0; i < 2; ++i)
      #pragma unroll
      for (int r = 0; r < 4; ++r){
        int rr = w*32 + i*16 + quad*4 + r;
        int key = (rr ^ (rr>>2)) & 7;
        int rbase = (rr<<6) + (col&7);
        float ps[4];
        #pragma unroll
        for (int j = 0; j < 4; ++j){
          float pv = __builtin_amdgcn_exp2f(s[i][j][r]*scale2);
          ps[j] = pv;
          Ps[rbase + ((((j*16+col)>>3) ^ key)<<3)] = f2bf(pv);
        }
        lsum[i*4+r] += (ps[0]+ps[1]) + (ps[2]+ps[3]);
      }

    // O += P V^T (Ps wave-private: in-wave lgkm ordering suffices, no barrier)
    const u16* Vc = Vs + ((t&1)<<13);
    #pragma unroll
    for (int kk = 0; kk < 2; ++kk){
      v8bf ap[2];
      #pragma unroll
      for (int i = 0; i < 2; ++i){
        int rr = w*32 + i*16 + col;
        int key = (rr ^ (rr>>2)) & 7;
        int g = (kk*4 + quad) ^ key;
        ap[i] = *(const v8bf*)(Ps + (rr<<6) + (g<<3));
      }
      #pragma unroll
      for (int j = 0; j < 8; ++j){
        int vr = j*16 + col;
        int g = (kk*4 + quad) ^ (vr&7);
        v8bf bv = *(const v8bf*)(Vc + (vr<<6) + (g<<3));
        #pragma unroll
        for (int i = 0; i < 2; ++i) o[i][j] = MFMA16(ap[i], bv, o[i][j]);
      }
    }
  }
  __syncthreads();

  // reduce l across the 16 col-lanes; normalize
  #pragma unroll
  for (int i = 0; i < 2; ++i)
    #pragma unroll
    for (int r = 0; r < 4; ++r){
      float l = lsum[i*4+r];
      l += __shfl_xor(l, 1);
      l += __shfl_xor(l, 2);
      l += __shfl_xor(l, 4);
      l += __shfl_xor(l, 8);
      float inv = 1.f / l;
      #pragma unroll
      for (int j = 0; j < 8; ++j) o[i][j][r] *= inv;
    }

  // bounce O through LDS (swizzled [128][128]) for coalesced 16B stores
  #pragma unroll
  for (int i = 0; i < 2; ++i)
    #pragma unroll
    for (int j = 0; j < 8; ++j)
      #pragma unroll
      for (int r = 0; r < 4; ++r){
        int rr = w*32 + i*16 + quad*4 + r;
        int c  = j*16 + col;
        smem[(rr<<7) + ((((c>>3) ^ (rr&7))<<3)) + (c&7)] = f2bf(o[i][j][r]);
      }
  __syncthreads();
  #pragma unroll
  for (int p = 0; p < 8; ++p){
    int nr = p*16 + (tid>>4);
    int gc = (tid&15) ^ (nr&7);
    *(int4*)(outp + ((size_t)b*1024 + n0 + nr)*512 + h*128 + ((tid&15)<<3)) =
      *(int4*)(smem + (nr<<7) + (gc<<3));
  }
}

extern "C" void kernel_launch(void* const* d_in, const int* in_sizes, int n_in,
                              void* d_out, int out_size, void* d_ws, size_t ws_size,
                              hipStream_t stream){
  const float* x      = (const float*)d_in[0];
  const float* norm_w = (const float*)d_in[1];
  const float* norm_b = (const float*)d_in[2];
  const float* qkv_w  = (const float*)d_in[3];
  const float* qkv_b  = (const float*)d_in[4];
  const float* proj_w = (const float*)d_in[5];
  const float* proj_b = (const float*)d_in[6];
  float* out = (float*)d_out;

  u16* h_t   = (u16*)d_ws;                                  // [16][1024][512]
  u16* qk_t  = h_t  + (size_t)16*1024*512;                  // [16][1024][1024]
  u16* v_ws  = qk_t + (size_t)16*1024*1024;                 // [16][512][1024]
  u16* wq_bf = v_ws + (size_t)16*512*1024;                  // [1536][512]
  u16* wp_bf = wq_bf + (size_t)1536*512;                    // [512][512]
  u16* attnout = h_t;                                       // reuse

  cvt2_kernel<<<1024, 256, 0, stream>>>(qkv_w, wq_bf, 1536*512, proj_w, wp_bf, 512*512);
  gn_fused_kernel<<<512, 256, 0, stream>>>(x, norm_w, norm_b, h_t);

  gemm_qkv_kernel<<<dim3(6,8,16), 256, 0, stream>>>(h_t, wq_bf, qkv_b, qk_t, v_ws);

  attn_kernel<<<512, 256, 0, stream>>>(qk_t, v_ws, attnout);

  gemm_bt_kernel<<<dim3(8,4,16), 256, 0, stream>>>(
      wp_bf, 0, attnout, (long long)1024*512,
      nullptr, out, (long long)512*1024, proj_b, nullptr, x, (long long)512*1024, 512, 1024, 512);
}